// Round 2
// baseline (1819.388 us; speedup 1.0000x reference)
//
#include <hip/hip_runtime.h>
#include <hip/hip_bf16.h>
#include <cstdint>
#include <cstddef>

// Problem constants: S=2048, B=4, H=2048, NH=16, HD=128
#define TOK 8192      // S*B rows of the activation matrix
#define HDIM 2048
#define H3 6144       // 3*H

typedef float f32x4 __attribute__((ext_vector_type(4)));
typedef short bf16x8 __attribute__((ext_vector_type(8)));   // 8 bf16 in 4 VGPRs (guide §3)
typedef unsigned short u16;
typedef unsigned int u32;
typedef u32 u32x2 __attribute__((ext_vector_type(2)));
typedef u32 u32x4 __attribute__((ext_vector_type(4)));

__device__ __forceinline__ u16 f2bf(float f) {
  union { float f; u32 u; } v; v.f = f;
  u32 u = v.u;
  return (u16)((u + 0x7fffu + ((u >> 16) & 1u)) >> 16);   // RNE
}

__device__ __forceinline__ void gload16(const void* g, void* l) {
  // async global->LDS, 16B per lane; LDS dest is wave-uniform base + lane*16
  __builtin_amdgcn_global_load_lds((const __attribute__((address_space(1))) u32*)g,
                                   (__attribute__((address_space(3))) u32*)l, 16, 0, 0);
}

// ---------------- fp32 -> bf16 weight conversion ----------------
__global__ __launch_bounds__(256)
void cvt_kernel(const float* __restrict__ in, u16* __restrict__ out, int n4) {
  int i = blockIdx.x * 256 + threadIdx.x;
  if (i >= n4) return;
  float4 v = ((const float4*)in)[i];
  union { u16 o[4]; u32x2 d; } t;
  t.o[0] = f2bf(v.x); t.o[1] = f2bf(v.y); t.o[2] = f2bf(v.z); t.o[3] = f2bf(v.w);
  ((u32x2*)out)[i] = t.d;
}

// ---------------- LayerNorm (fp32 in, bf16 out), one row per block ----------------
__global__ __launch_bounds__(256)
void ln_kernel(const float* __restrict__ x, const float* __restrict__ g,
               const float* __restrict__ bta, u16* __restrict__ out) {
  const int row = blockIdx.x, tid = threadIdx.x;
  const int lane = tid & 63, w = tid >> 6;
  const float* xr = x + (size_t)row * HDIM + tid * 8;
  float4 a = *(const float4*)xr;
  float4 c = *(const float4*)(xr + 4);
  float s = a.x + a.y + a.z + a.w + c.x + c.y + c.z + c.w;
  float q = a.x*a.x + a.y*a.y + a.z*a.z + a.w*a.w + c.x*c.x + c.y*c.y + c.z*c.z + c.w*c.w;
#pragma unroll
  for (int m = 32; m >= 1; m >>= 1) { s += __shfl_xor(s, m, 64); q += __shfl_xor(q, m, 64); }
  __shared__ float red[8];
  if (lane == 0) { red[w] = s; red[4 + w] = q; }
  __syncthreads();
  s = red[0] + red[1] + red[2] + red[3];
  q = red[4] + red[5] + red[6] + red[7];
  const float mu = s * (1.0f / HDIM);
  const float rstd = rsqrtf(q * (1.0f / HDIM) - mu * mu + 1e-5f);
  const float* gp = g + tid * 8; const float* bp = bta + tid * 8;
  float4 g0 = *(const float4*)gp, g1 = *(const float4*)(gp + 4);
  float4 b0 = *(const float4*)bp, b1 = *(const float4*)(bp + 4);
  union { u16 o[8]; u32x4 d; } t;
  t.o[0] = f2bf((a.x - mu) * rstd * g0.x + b0.x);
  t.o[1] = f2bf((a.y - mu) * rstd * g0.y + b0.y);
  t.o[2] = f2bf((a.z - mu) * rstd * g0.z + b0.z);
  t.o[3] = f2bf((a.w - mu) * rstd * g0.w + b0.w);
  t.o[4] = f2bf((c.x - mu) * rstd * g1.x + b1.x);
  t.o[5] = f2bf((c.y - mu) * rstd * g1.y + b1.y);
  t.o[6] = f2bf((c.z - mu) * rstd * g1.z + b1.z);
  t.o[7] = f2bf((c.w - mu) * rstd * g1.w + b1.w);
  *(u32x4*)(out + (size_t)row * HDIM + tid * 8) = t.d;
}

// ---------------- GEMM: C[M,N] = A[M,K](bf16) @ B[N,K]^T(bf16) + bias ----------------
// EPI 0: bf16 out;  1: GELU(exact) -> bf16 out;  2: + resid(fp32) -> fp32 out
template <int EPI>
__global__ __launch_bounds__(256, 2)
void gemm_bt(const u16* __restrict__ A, const u16* __restrict__ Bm,
             const float* __restrict__ bias, const float* __restrict__ resid,
             u16* __restrict__ Cb, float* __restrict__ Cf, int M, int N, int K) {
  __shared__ u16 lsA[128 * 32];
  __shared__ u16 lsB[128 * 32];
  const int tid = threadIdx.x;
  const int lane = tid & 63, w = tid >> 6;
  const int tm = blockIdx.y * 128, tn = blockIdx.x * 128;
  const int wr = w >> 1, wc = w & 1;

  f32x4 acc[4][4] = {};

  const u16* gA = A + (size_t)(tm + w * 32 + (lane >> 2)) * K + (lane & 3) * 8;
  const u16* gB = Bm + (size_t)(tn + w * 32 + (lane >> 2)) * K + (lane & 3) * 8;
  u16* lA = lsA + w * 1024;
  u16* lB = lsB + w * 1024;

  const int kiters = K >> 5;
  for (int kt = 0; kt < kiters; ++kt) {
    __syncthreads();                        // prior compute done before overwrite
    gload16(gA, lA);
    gload16(gA + (size_t)16 * K, lA + 512);
    gload16(gB, lB);
    gload16(gB + (size_t)16 * K, lB + 512);
    gA += 32; gB += 32;
    __syncthreads();                        // compiler drains vmcnt(0) before barrier

    const char* pa = (const char*)lsA + ((wr * 64 + (lane & 15)) * 32 + (lane >> 4) * 8) * 2;
    const char* pb = (const char*)lsB + ((wc * 64 + (lane & 15)) * 32 + (lane >> 4) * 8) * 2;
    bf16x8 af[4], bfr[4];
#pragma unroll
    for (int i = 0; i < 4; ++i) {
      af[i]  = *(const bf16x8*)(pa + i * 1024);   // +16 rows = 16*64B
      bfr[i] = *(const bf16x8*)(pb + i * 1024);
    }
#pragma unroll
    for (int mi = 0; mi < 4; ++mi)
#pragma unroll
      for (int ni = 0; ni < 4; ++ni)
        acc[mi][ni] = __builtin_amdgcn_mfma_f32_16x16x32_bf16(af[mi], bfr[ni], acc[mi][ni], 0, 0, 0);
  }

  const int colbase = tn + wc * 64 + (lane & 15);
  const int rowbase = tm + wr * 64 + (lane >> 4) * 4;
#pragma unroll
  for (int mi = 0; mi < 4; ++mi) {
#pragma unroll
    for (int ni = 0; ni < 4; ++ni) {
      const int col = colbase + ni * 16;
      const float bv = bias[col];
#pragma unroll
      for (int r = 0; r < 4; ++r) {
        const int row = rowbase + mi * 16 + r;
        float v = acc[mi][ni][r] + bv;
        if constexpr (EPI == 1) v = 0.5f * v * (1.0f + erff(v * 0.70710678118654752f));
        const size_t idx = (size_t)row * N + col;
        if constexpr (EPI == 2) Cf[idx] = v + resid[idx];
        else                    Cb[idx] = f2bf(v);
      }
    }
  }
}

// ---------------- Flash attention (causal, 16 heads, HD=128) ----------------
// Correctness-first rebuild: only verified primitives.
//   K tile: linear [32][128] LDS via plain vector loads + ds_write_b128.
//   V tile: transposed [128][32] LDS via register round-trip, so the PV
//           B-operand is a contiguous bf16x8 read (same shape as GEMM B).
//   P bounce: plain (unswizzled) per-wave [16][32] LDS.
// grid (32 q-tiles, 64 b*h). Block: 4 waves, each wave owns 16 q-rows.
__global__ __launch_bounds__(256, 2)
void attn_kernel(const u16* __restrict__ qkv, u16* __restrict__ outb) {
  const int qt = blockIdx.x;
  const int bh = blockIdx.y;
  const int b = bh >> 4, h = bh & 15;
  const int tid = threadIdx.x, lane = tid & 63, w = tid >> 6;
  const int qs = qt * 64;

  __shared__ u16 Klds[32 * 128];          // [kv][d] linear
  __shared__ u16 Vt[128 * 32];            // [d][kv] transposed
  __shared__ u16 Plds[4 * 16 * 32];       // per-wave P bounce, plain [16][32]

  // Q fragments: 16 rows x 128, 4 k-steps of 32
  bf16x8 qf[4];
  {
    const int qrow = qs + w * 16 + (lane & 15);
    const u16* qp = qkv + (size_t)(qrow * 4 + b) * H3 + h * 128 + (lane >> 4) * 8;
#pragma unroll
    for (int kc = 0; kc < 4; ++kc) qf[kc] = *(const bf16x8*)(qp + kc * 32);
  }

  f32x4 o[8] = {};
  float mrun[4], lrun[4];
#pragma unroll
  for (int r = 0; r < 4; ++r) { mrun[r] = -1e30f; lrun[r] = 0.0f; }

  const int ntiles = (qs + 64) >> 5;
  const int wqmin = qs + w * 16;
  const float sc = 0.08838834764831845f;   // 1/sqrt(128)

  u16* plb = Plds + w * 512;               // 16*32 u16 per wave

  const int srow = tid >> 3;               // staging: kv row 0..31
  const int scol = (tid & 7) * 16;         // staging: d col 0..112

  for (int kt = 0; kt < ntiles; ++kt) {
    const int kv0 = kt * 32;
    // K/V tile -> registers (coalesced global reads)
    const u16* ksrc = qkv + (size_t)((kv0 + srow) * 4 + b) * H3 + 2048 + h * 128 + scol;
    const u16* vsrc = qkv + (size_t)((kv0 + srow) * 4 + b) * H3 + 4096 + h * 128 + scol;
    bf16x8 k0 = *(const bf16x8*)ksrc;
    bf16x8 k1 = *(const bf16x8*)(ksrc + 8);
    bf16x8 v0 = *(const bf16x8*)vsrc;
    bf16x8 v1 = *(const bf16x8*)(vsrc + 8);

    __syncthreads();                       // all waves done reading previous tile
    *(bf16x8*)(Klds + srow * 128 + scol)     = k0;
    *(bf16x8*)(Klds + srow * 128 + scol + 8) = k1;
#pragma unroll
    for (int j = 0; j < 8; ++j) {
      Vt[(scol + j) * 32 + srow]     = (u16)v0[j];
      Vt[(scol + 8 + j) * 32 + srow] = (u16)v1[j];
    }
    __syncthreads();                       // staging visible to all waves

    // S = Q @ K^T   (A: Q rows; B: K rows as columns, contiguous-d reads)
    f32x4 s0 = {0, 0, 0, 0}, s1 = {0, 0, 0, 0};
#pragma unroll
    for (int kc = 0; kc < 4; ++kc) {
      const int doff = kc * 32 + (lane >> 4) * 8;
      bf16x8 kfa = *(const bf16x8*)(Klds + (lane & 15) * 128 + doff);
      bf16x8 kfb = *(const bf16x8*)(Klds + (16 + (lane & 15)) * 128 + doff);
      s0 = __builtin_amdgcn_mfma_f32_16x16x32_bf16(qf[kc], kfa, s0, 0, 0, 0);
      s1 = __builtin_amdgcn_mfma_f32_16x16x32_bf16(qf[kc], kfb, s1, 0, 0, 0);
    }
#pragma unroll
    for (int r = 0; r < 4; ++r) { s0[r] *= sc; s1[r] *= sc; }

    // causal mask (kv > qrow  ->  -inf)
    if (kv0 + 31 > wqmin) {
#pragma unroll
      for (int r = 0; r < 4; ++r) {
        const int qrow = wqmin + (lane >> 4) * 4 + r;
        if (kv0 + (lane & 15) > qrow)      s0[r] = -1e30f;
        if (kv0 + 16 + (lane & 15) > qrow) s1[r] = -1e30f;
      }
    }

    // online softmax: row (lane>>4)*4+r lives on the 16 lanes of this group
    float pm[4];
#pragma unroll
    for (int r = 0; r < 4; ++r) pm[r] = fmaxf(s0[r], s1[r]);
#pragma unroll
    for (int m = 8; m >= 1; m >>= 1)
#pragma unroll
      for (int r = 0; r < 4; ++r) pm[r] = fmaxf(pm[r], __shfl_xor(pm[r], m, 64));

    float p0[4], p1[4], rs[4], corr[4];
#pragma unroll
    for (int r = 0; r < 4; ++r) {
      const float mnew = fmaxf(mrun[r], pm[r]);
      corr[r] = __expf(mrun[r] - mnew);
      p0[r] = __expf(s0[r] - mnew);
      p1[r] = __expf(s1[r] - mnew);
      rs[r] = p0[r] + p1[r];
      mrun[r] = mnew;
    }
#pragma unroll
    for (int m = 8; m >= 1; m >>= 1)
#pragma unroll
      for (int r = 0; r < 4; ++r) rs[r] += __shfl_xor(rs[r], m, 64);
#pragma unroll
    for (int r = 0; r < 4; ++r) lrun[r] = lrun[r] * corr[r] + rs[r];
#pragma unroll
    for (int nf = 0; nf < 8; ++nf)
#pragma unroll
      for (int r = 0; r < 4; ++r) o[nf][r] *= corr[r];

    // P (C-layout) -> wave-private LDS (plain) -> A-layout fragment
#pragma unroll
    for (int r = 0; r < 4; ++r) {
      const int prow = ((lane >> 4) << 2) + r;
      plb[prow * 32 + (lane & 15)]      = f2bf(p0[r]);
      plb[prow * 32 + 16 + (lane & 15)] = f2bf(p1[r]);
    }
    asm volatile("s_waitcnt lgkmcnt(0)" ::: "memory");   // same-wave ds order + compiler fence
    bf16x8 pf = *(const bf16x8*)(plb + (lane & 15) * 32 + (lane >> 4) * 8);

    // PV: B-operand from transposed V (contiguous kv per lane, GEMM-B shape)
#pragma unroll
    for (int nf = 0; nf < 8; ++nf) {
      bf16x8 vf = *(const bf16x8*)(Vt + (nf * 16 + (lane & 15)) * 32 + (lane >> 4) * 8);
      o[nf] = __builtin_amdgcn_mfma_f32_16x16x32_bf16(pf, vf, o[nf], 0, 0, 0);
    }
  }

  float inv[4];
#pragma unroll
  for (int r = 0; r < 4; ++r) inv[r] = 1.0f / lrun[r];
#pragma unroll
  for (int nf = 0; nf < 8; ++nf) {
#pragma unroll
    for (int r = 0; r < 4; ++r) {
      const int rl = (lane >> 4) * 4 + r;
      const int t = (qs + w * 16 + rl) * 4 + b;
      outb[(size_t)t * HDIM + h * 128 + nf * 16 + (lane & 15)] = f2bf(o[nf][r] * inv[r]);
    }
  }
}

// ---------------- launcher ----------------
extern "C" void kernel_launch(void* const* d_in, const int* in_sizes, int n_in,
                              void* d_out, int out_size, void* d_ws, size_t ws_size,
                              hipStream_t stream) {
  const float* x     = (const float*)d_in[0];
  const float* ln1g  = (const float*)d_in[1];
  const float* ln1b  = (const float*)d_in[2];
  const float* qkvw  = (const float*)d_in[3];
  const float* qkvb  = (const float*)d_in[4];
  const float* projw = (const float*)d_in[5];
  const float* projb = (const float*)d_in[6];
  const float* ln2g  = (const float*)d_in[7];
  const float* ln2b  = (const float*)d_in[8];
  const float* fc1w  = (const float*)d_in[9];
  const float* fc1b  = (const float*)d_in[10];
  const float* fc2w  = (const float*)d_in[11];
  const float* fc2b  = (const float*)d_in[12];
  float* out = (float*)d_out;

  // ws layout (201.3 MB): [wbuf 32MiB][pbuf 32MiB][qbuf 128MiB]
  u16* wbuf = (u16*)d_ws;
  u16* pbuf = (u16*)((char*)d_ws + 33554432);
  u16* qbuf = (u16*)((char*)d_ws + 67108864);

  dim3 blk(256);

  // LN1 -> pbuf (bf16)
  ln_kernel<<<8192, blk, 0, stream>>>(x, ln1g, ln1b, pbuf);
  // qkv_w -> bf16
  cvt_kernel<<<12288, blk, 0, stream>>>(qkvw, wbuf, 3145728);
  // qkv = h @ qkv_w^T + b  -> qbuf [8192 x 6144] bf16
  gemm_bt<0><<<dim3(48, 64), blk, 0, stream>>>(pbuf, wbuf, qkvb, nullptr, qbuf, nullptr, 8192, 6144, 2048);
  // attention -> pbuf [8192 x 2048] bf16
  attn_kernel<<<dim3(32, 64), blk, 0, stream>>>(qbuf, pbuf);
  // proj_w -> bf16
  cvt_kernel<<<4096, blk, 0, stream>>>(projw, wbuf, 1048576);
  // x2 = x + attn @ proj_w^T + b  -> d_out (fp32)
  gemm_bt<2><<<dim3(16, 64), blk, 0, stream>>>(pbuf, wbuf, projb, x, nullptr, out, 8192, 2048, 2048);
  // LN2 -> pbuf (bf16)
  ln_kernel<<<8192, blk, 0, stream>>>(out, ln2g, ln2b, pbuf);
  // fc1_w -> bf16
  cvt_kernel<<<16384, blk, 0, stream>>>(fc1w, wbuf, 4194304);
  // h = gelu(ln2 @ fc1_w^T + b) -> qbuf [8192 x 8192] bf16
  gemm_bt<1><<<dim3(64, 64), blk, 0, stream>>>(pbuf, wbuf, fc1b, nullptr, qbuf, nullptr, 8192, 8192, 2048);
  // fc2_w -> bf16
  cvt_kernel<<<16384, blk, 0, stream>>>(fc2w, wbuf, 4194304);
  // out = x2 + h @ fc2_w^T + b  (in-place residual on d_out)
  gemm_bt<2><<<dim3(16, 64), blk, 0, stream>>>(qbuf, wbuf, fc2b, out, nullptr, out, 8192, 2048, 8192);
}

// Round 3
// 1417.018 us; speedup vs baseline: 1.2840x; 1.2840x over previous
//
#include <hip/hip_runtime.h>
#include <hip/hip_bf16.h>
#include <cstdint>
#include <cstddef>

// Problem constants: S=2048, B=4, H=2048, NH=16, HD=128
#define TOK 8192      // S*B rows of the activation matrix
#define HDIM 2048
#define H3 6144       // 3*H

typedef float f32x4 __attribute__((ext_vector_type(4)));
typedef short bf16x8 __attribute__((ext_vector_type(8)));   // 8 bf16 in 4 VGPRs (guide §3)
typedef unsigned short u16;
typedef unsigned int u32;
typedef u32 u32x2 __attribute__((ext_vector_type(2)));
typedef u32 u32x4 __attribute__((ext_vector_type(4)));

__device__ __forceinline__ u16 f2bf(float f) {
  union { float f; u32 u; } v; v.f = f;
  u32 u = v.u;
  return (u16)((u + 0x7fffu + ((u >> 16) & 1u)) >> 16);   // RNE
}

__device__ __forceinline__ void gload16(const void* g, void* l) {
  // async global->LDS, 16B per lane; LDS dest is wave-uniform base + lane*16
  __builtin_amdgcn_global_load_lds((const __attribute__((address_space(1))) u32*)g,
                                   (__attribute__((address_space(3))) u32*)l, 16, 0, 0);
}

// ---------------- fp32 -> bf16 weight conversion ----------------
__global__ __launch_bounds__(256)
void cvt_kernel(const float* __restrict__ in, u16* __restrict__ out, int n4) {
  int i = blockIdx.x * 256 + threadIdx.x;
  if (i >= n4) return;
  float4 v = ((const float4*)in)[i];
  union { u16 o[4]; u32x2 d; } t;
  t.o[0] = f2bf(v.x); t.o[1] = f2bf(v.y); t.o[2] = f2bf(v.z); t.o[3] = f2bf(v.w);
  ((u32x2*)out)[i] = t.d;
}

// ---------------- LayerNorm (fp32 in, bf16 out), one row per block ----------------
__global__ __launch_bounds__(256)
void ln_kernel(const float* __restrict__ x, const float* __restrict__ g,
               const float* __restrict__ bta, u16* __restrict__ out) {
  const int row = blockIdx.x, tid = threadIdx.x;
  const int lane = tid & 63, w = tid >> 6;
  const float* xr = x + (size_t)row * HDIM + tid * 8;
  float4 a = *(const float4*)xr;
  float4 c = *(const float4*)(xr + 4);
  float s = a.x + a.y + a.z + a.w + c.x + c.y + c.z + c.w;
  float q = a.x*a.x + a.y*a.y + a.z*a.z + a.w*a.w + c.x*c.x + c.y*c.y + c.z*c.z + c.w*c.w;
#pragma unroll
  for (int m = 32; m >= 1; m >>= 1) { s += __shfl_xor(s, m, 64); q += __shfl_xor(q, m, 64); }
  __shared__ float red[8];
  if (lane == 0) { red[w] = s; red[4 + w] = q; }
  __syncthreads();
  s = red[0] + red[1] + red[2] + red[3];
  q = red[4] + red[5] + red[6] + red[7];
  const float mu = s * (1.0f / HDIM);
  const float rstd = rsqrtf(q * (1.0f / HDIM) - mu * mu + 1e-5f);
  const float* gp = g + tid * 8; const float* bp = bta + tid * 8;
  float4 g0 = *(const float4*)gp, g1 = *(const float4*)(gp + 4);
  float4 b0 = *(const float4*)bp, b1 = *(const float4*)(bp + 4);
  union { u16 o[8]; u32x4 d; } t;
  t.o[0] = f2bf((a.x - mu) * rstd * g0.x + b0.x);
  t.o[1] = f2bf((a.y - mu) * rstd * g0.y + b0.y);
  t.o[2] = f2bf((a.z - mu) * rstd * g0.z + b0.z);
  t.o[3] = f2bf((a.w - mu) * rstd * g0.w + b0.w);
  t.o[4] = f2bf((c.x - mu) * rstd * g1.x + b1.x);
  t.o[5] = f2bf((c.y - mu) * rstd * g1.y + b1.y);
  t.o[6] = f2bf((c.z - mu) * rstd * g1.z + b1.z);
  t.o[7] = f2bf((c.w - mu) * rstd * g1.w + b1.w);
  *(u32x4*)(out + (size_t)row * HDIM + tid * 8) = t.d;
}

// ---------------- GEMM: C[M,N] = A[M,K](bf16) @ B[N,K]^T(bf16) + bias ----------------
// EPI 0: bf16 out;  1: GELU(exact) -> bf16 out;  2: + resid(fp32) -> fp32 out
template <int EPI>
__global__ __launch_bounds__(256, 2)
void gemm_bt(const u16* __restrict__ A, const u16* __restrict__ Bm,
             const float* __restrict__ bias, const float* __restrict__ resid,
             u16* __restrict__ Cb, float* __restrict__ Cf, int M, int N, int K) {
  __shared__ u16 lsA[128 * 32];
  __shared__ u16 lsB[128 * 32];
  const int tid = threadIdx.x;
  const int lane = tid & 63, w = tid >> 6;
  const int tm = blockIdx.y * 128, tn = blockIdx.x * 128;
  const int wr = w >> 1, wc = w & 1;

  f32x4 acc[4][4] = {};

  const u16* gA = A + (size_t)(tm + w * 32 + (lane >> 2)) * K + (lane & 3) * 8;
  const u16* gB = Bm + (size_t)(tn + w * 32 + (lane >> 2)) * K + (lane & 3) * 8;
  u16* lA = lsA + w * 1024;
  u16* lB = lsB + w * 1024;

  const int kiters = K >> 5;
  for (int kt = 0; kt < kiters; ++kt) {
    __syncthreads();                        // prior compute done before overwrite
    gload16(gA, lA);
    gload16(gA + (size_t)16 * K, lA + 512);
    gload16(gB, lB);
    gload16(gB + (size_t)16 * K, lB + 512);
    gA += 32; gB += 32;
    __syncthreads();                        // compiler drains vmcnt(0) before barrier

    const char* pa = (const char*)lsA + ((wr * 64 + (lane & 15)) * 32 + (lane >> 4) * 8) * 2;
    const char* pb = (const char*)lsB + ((wc * 64 + (lane & 15)) * 32 + (lane >> 4) * 8) * 2;
    bf16x8 af[4], bfr[4];
#pragma unroll
    for (int i = 0; i < 4; ++i) {
      af[i]  = *(const bf16x8*)(pa + i * 1024);   // +16 rows = 16*64B
      bfr[i] = *(const bf16x8*)(pb + i * 1024);
    }
#pragma unroll
    for (int mi = 0; mi < 4; ++mi)
#pragma unroll
      for (int ni = 0; ni < 4; ++ni)
        acc[mi][ni] = __builtin_amdgcn_mfma_f32_16x16x32_bf16(af[mi], bfr[ni], acc[mi][ni], 0, 0, 0);
  }

  const int colbase = tn + wc * 64 + (lane & 15);
  const int rowbase = tm + wr * 64 + (lane >> 4) * 4;
#pragma unroll
  for (int mi = 0; mi < 4; ++mi) {
#pragma unroll
    for (int ni = 0; ni < 4; ++ni) {
      const int col = colbase + ni * 16;
      const float bv = bias[col];
#pragma unroll
      for (int r = 0; r < 4; ++r) {
        const int row = rowbase + mi * 16 + r;
        float v = acc[mi][ni][r] + bv;
        if constexpr (EPI == 1) v = 0.5f * v * (1.0f + erff(v * 0.70710678118654752f));
        const size_t idx = (size_t)row * N + col;
        if constexpr (EPI == 2) Cf[idx] = v + resid[idx];
        else                    Cb[idx] = f2bf(v);
      }
    }
  }
}

// ---------------- V transpose: qkv V part -> Vt_g[bh][d][s] ----------------
// grid (64 s-tiles, 64 bh), block 256. LDS tile [32 s][136 u16] (pad keeps
// 16B-aligned rows, breaks bank alignment for the column gather).
__global__ __launch_bounds__(256)
void vtrans_kernel(const u16* __restrict__ qkv, u16* __restrict__ vt) {
  __shared__ u16 tile[32 * 136];
  const int s0 = blockIdx.x * 32;
  const int bh = blockIdx.y;
  const int b = bh >> 4, h = bh & 15;
  const int t = threadIdx.x;
  const int srow = t >> 3, scol = (t & 7) * 16;
  const u16* src = qkv + (size_t)((s0 + srow) * 4 + b) * H3 + 4096 + h * 128 + scol;
  *(bf16x8*)(tile + srow * 136 + scol)     = *(const bf16x8*)src;
  *(bf16x8*)(tile + srow * 136 + scol + 8) = *(const bf16x8*)(src + 8);
  __syncthreads();
  const int d = t >> 1, sc = (t & 1) * 16;
  union { u16 o[16]; u32x4 q[2]; } tmp;
#pragma unroll
  for (int i = 0; i < 16; ++i) tmp.o[i] = tile[(sc + i) * 136 + d];
  u16* dst = vt + ((size_t)bh * 128 + d) * 2048 + s0 + sc;
  *(u32x4*)dst       = tmp.q[0];
  *(u32x4*)(dst + 8) = tmp.q[1];
}

// ---------------- Flash attention (causal, 16 heads, HD=128) ----------------
// KVBLK=64. K staged [64][128] XOR-swizzled; V staged from pre-transposed
// Vt_g as [128 d][64 kv] XOR-swizzled; P bounce [16][64] per wave, swizzled.
// All hot LDS reads are b128 and slot-uniform (conflict-free).
// grid (32 q-tiles desc, 64 b*h). Block: 4 waves, each wave owns 16 q-rows.
__global__ __launch_bounds__(256, 2)
void attn_kernel(const u16* __restrict__ qkv, const u16* __restrict__ vt,
                 u16* __restrict__ outb) {
  const int qt = 31 - blockIdx.x;          // long blocks dispatch first
  const int bh = blockIdx.y;
  const int b = bh >> 4, h = bh & 15;
  const int tid = threadIdx.x, lane = tid & 63, w = tid >> 6;
  const int hi = lane >> 4, l15 = lane & 15;
  const int qs = qt * 64;

  __shared__ u16 Klds[64 * 128];           // [kv][d], rows 256B, swizzled
  __shared__ u16 Vlds[128 * 64];           // [d][kv], rows 128B, swizzled
  __shared__ u16 Plds[4 * 16 * 64];        // per-wave [16 q][64 kv], swizzled

  // Q fragments: 16 rows x 128, 4 k-steps of 32
  bf16x8 qf[4];
  {
    const int qrow = qs + w * 16 + l15;
    const u16* qp = qkv + (size_t)(qrow * 4 + b) * H3 + h * 128 + hi * 8;
#pragma unroll
    for (int kc = 0; kc < 4; ++kc) qf[kc] = *(const bf16x8*)(qp + kc * 32);
  }

  f32x4 o[8] = {};
  float mrun[4], lrun[4];
#pragma unroll
  for (int r = 0; r < 4; ++r) { mrun[r] = -1e30f; lrun[r] = 0.0f; }

  const float sc = 0.08838834764831845f;   // 1/sqrt(128)
  char* plb = (char*)(Plds + w * 1024);

  // staging assignments
  const int krow = tid >> 2;               // 0..63 kv row
  const int kcb  = (tid & 3) * 64;         // byte col in K row
  const int vd   = tid >> 1;               // 0..127 d row
  const int vhb  = (tid & 1) * 64;         // byte col in Vt row

  const int ntiles = qt + 1;
  for (int kt = 0; kt < ntiles; ++kt) {
    const int kv0 = kt * 64;
    // tile -> registers (issue loads before the barrier: overlap with prev compute)
    const u16* ksrc = qkv + (size_t)((kv0 + krow) * 4 + b) * H3 + 2048 + h * 128 + kcb / 2;
    const u16* vsrc = vt + ((size_t)bh * 128 + vd) * 2048 + kv0 + (tid & 1) * 32;
    bf16x8 kr[4], vr[4];
#pragma unroll
    for (int c = 0; c < 4; ++c) { kr[c] = *(const bf16x8*)(ksrc + c * 8); vr[c] = *(const bf16x8*)(vsrc + c * 8); }

    __syncthreads();                       // all waves done reading previous tile
#pragma unroll
    for (int c = 0; c < 4; ++c) {
      *(bf16x8*)((char*)Klds + ((krow * 256 + kcb + c * 16) ^ ((krow & 7) << 4))) = kr[c];
      *(bf16x8*)((char*)Vlds + ((vd * 128 + vhb + c * 16) ^ ((vd & 7) << 4)))     = vr[c];
    }
    __syncthreads();                       // staging visible to all waves

    // S = Q @ K^T : 4 kv-groups of 16 cols
    f32x4 s[4] = {};
#pragma unroll
    for (int kc = 0; kc < 4; ++kc) {
      const int dbyte = kc * 64 + hi * 16;
#pragma unroll
      for (int g = 0; g < 4; ++g) {
        const int row = g * 16 + l15;
        bf16x8 kf = *(const bf16x8*)((char*)Klds + ((row * 256 + dbyte) ^ ((l15 & 7) << 4)));
        s[g] = __builtin_amdgcn_mfma_f32_16x16x32_bf16(qf[kc], kf, s[g], 0, 0, 0);
      }
    }
#pragma unroll
    for (int g = 0; g < 4; ++g)
#pragma unroll
      for (int r = 0; r < 4; ++r) s[g][r] *= sc;

    // causal mask (diagonal tile only)
    if (kt == qt) {
#pragma unroll
      for (int g = 0; g < 4; ++g)
#pragma unroll
        for (int r = 0; r < 4; ++r) {
          const int qrel = w * 16 + hi * 4 + r;
          if (g * 16 + l15 > qrel) s[g][r] = -1e30f;
        }
    }

    // online softmax: q-row (hi*4+r) lives on the 16 lanes of this quarter
    float pm[4];
#pragma unroll
    for (int r = 0; r < 4; ++r)
      pm[r] = fmaxf(fmaxf(s[0][r], s[1][r]), fmaxf(s[2][r], s[3][r]));
#pragma unroll
    for (int m = 8; m >= 1; m >>= 1)
#pragma unroll
      for (int r = 0; r < 4; ++r) pm[r] = fmaxf(pm[r], __shfl_xor(pm[r], m, 64));

    float corr[4], rs[4];
    float p[4][4];
#pragma unroll
    for (int r = 0; r < 4; ++r) {
      const float mnew = fmaxf(mrun[r], pm[r]);
      corr[r] = __expf(mrun[r] - mnew);
      mrun[r] = mnew;
      rs[r] = 0.0f;
    }
#pragma unroll
    for (int g = 0; g < 4; ++g)
#pragma unroll
      for (int r = 0; r < 4; ++r) { p[g][r] = __expf(s[g][r] - mrun[r]); rs[r] += p[g][r]; }
#pragma unroll
    for (int m = 8; m >= 1; m >>= 1)
#pragma unroll
      for (int r = 0; r < 4; ++r) rs[r] += __shfl_xor(rs[r], m, 64);
#pragma unroll
    for (int r = 0; r < 4; ++r) lrun[r] = lrun[r] * corr[r] + rs[r];
#pragma unroll
    for (int nf = 0; nf < 8; ++nf)
#pragma unroll
      for (int r = 0; r < 4; ++r) o[nf][r] *= corr[r];

    // P (C-layout) -> wave-private swizzled LDS -> A-layout fragments
#pragma unroll
    for (int r = 0; r < 4; ++r) {
      const int prow = hi * 4 + r;
      const int sw = (prow & 7) << 4;
#pragma unroll
      for (int g = 0; g < 4; ++g)
        *(u16*)(plb + ((prow * 128 + (g * 16 + l15) * 2) ^ sw)) = f2bf(p[g][r]);
    }
    asm volatile("s_waitcnt lgkmcnt(0)" ::: "memory");   // same-wave ds order + compiler fence
    bf16x8 pf[2];
#pragma unroll
    for (int hk = 0; hk < 2; ++hk)
      pf[hk] = *(const bf16x8*)(plb + ((l15 * 128 + hk * 64 + hi * 16) ^ ((l15 & 7) << 4)));

    // PV: B-operand from transposed V in LDS (swizzled b128 reads)
#pragma unroll
    for (int hk = 0; hk < 2; ++hk)
#pragma unroll
      for (int nf = 0; nf < 8; ++nf) {
        bf16x8 vf = *(const bf16x8*)((char*)Vlds +
                      (((nf * 16 + l15) * 128 + hk * 64 + hi * 16) ^ ((l15 & 7) << 4)));
        o[nf] = __builtin_amdgcn_mfma_f32_16x16x32_bf16(pf[hk], vf, o[nf], 0, 0, 0);
      }
  }

  float inv[4];
#pragma unroll
  for (int r = 0; r < 4; ++r) inv[r] = 1.0f / lrun[r];
#pragma unroll
  for (int nf = 0; nf < 8; ++nf) {
#pragma unroll
    for (int r = 0; r < 4; ++r) {
      const int rl = hi * 4 + r;
      const int t = (qs + w * 16 + rl) * 4 + b;
      outb[(size_t)t * HDIM + h * 128 + nf * 16 + l15] = f2bf(o[nf][r] * inv[r]);
    }
  }
}

// ---------------- launcher ----------------
extern "C" void kernel_launch(void* const* d_in, const int* in_sizes, int n_in,
                              void* d_out, int out_size, void* d_ws, size_t ws_size,
                              hipStream_t stream) {
  const float* x     = (const float*)d_in[0];
  const float* ln1g  = (const float*)d_in[1];
  const float* ln1b  = (const float*)d_in[2];
  const float* qkvw  = (const float*)d_in[3];
  const float* qkvb  = (const float*)d_in[4];
  const float* projw = (const float*)d_in[5];
  const float* projb = (const float*)d_in[6];
  const float* ln2g  = (const float*)d_in[7];
  const float* ln2b  = (const float*)d_in[8];
  const float* fc1w  = (const float*)d_in[9];
  const float* fc1b  = (const float*)d_in[10];
  const float* fc2w  = (const float*)d_in[11];
  const float* fc2b  = (const float*)d_in[12];
  float* out = (float*)d_out;

  // ws layout (192 MiB total, same footprint as round 2):
  //   [0,32M)    wbuf  (weights bf16)           -- dead during attention
  //   [32M,64M)  pbuf  (LN outputs bf16)        -- dead during attention
  //   [0,64M)    vtg   (V transposed, attn-only) -- overlaps wbuf+pbuf
  //   [64M,192M) qbuf  (qkv / fc1 out bf16)
  //   [160M,192M) aout (attn out, dead region of qbuf during attn)
  u16* wbuf = (u16*)d_ws;
  u16* pbuf = (u16*)((char*)d_ws + (size_t)32 * 1024 * 1024);
  u16* qbuf = (u16*)((char*)d_ws + (size_t)64 * 1024 * 1024);
  u16* vtg  = (u16*)d_ws;
  u16* aout = (u16*)((char*)d_ws + (size_t)160 * 1024 * 1024);

  dim3 blk(256);

  // LN1 -> pbuf (bf16)
  ln_kernel<<<8192, blk, 0, stream>>>(x, ln1g, ln1b, pbuf);
  // qkv_w -> bf16
  cvt_kernel<<<12288, blk, 0, stream>>>(qkvw, wbuf, 3145728);
  // qkv = h @ qkv_w^T + b  -> qbuf [8192 x 6144] bf16
  gemm_bt<0><<<dim3(48, 64), blk, 0, stream>>>(pbuf, wbuf, qkvb, nullptr, qbuf, nullptr, 8192, 6144, 2048);
  // V -> Vt_g [bh][d][s]   (wbuf/pbuf contents dead here)
  vtrans_kernel<<<dim3(64, 64), blk, 0, stream>>>(qbuf, vtg);
  // attention -> aout [8192 x 2048] bf16
  attn_kernel<<<dim3(32, 64), blk, 0, stream>>>(qbuf, vtg, aout);
  // proj_w -> bf16 (vtg dead now)
  cvt_kernel<<<4096, blk, 0, stream>>>(projw, wbuf, 1048576);
  // x2 = x + attn @ proj_w^T + b  -> d_out (fp32)
  gemm_bt<2><<<dim3(16, 64), blk, 0, stream>>>(aout, wbuf, projb, x, nullptr, out, 8192, 2048, 2048);
  // LN2 -> pbuf (bf16)
  ln_kernel<<<8192, blk, 0, stream>>>(out, ln2g, ln2b, pbuf);
  // fc1_w -> bf16
  cvt_kernel<<<16384, blk, 0, stream>>>(fc1w, wbuf, 4194304);
  // h = gelu(ln2 @ fc1_w^T + b) -> qbuf [8192 x 8192] bf16 (aout dead now)
  gemm_bt<1><<<dim3(64, 64), blk, 0, stream>>>(pbuf, wbuf, fc1b, nullptr, qbuf, nullptr, 8192, 8192, 2048);
  // fc2_w -> bf16
  cvt_kernel<<<16384, blk, 0, stream>>>(fc2w, wbuf, 4194304);
  // out = x2 + h @ fc2_w^T + b  (in-place residual on d_out)
  gemm_bt<2><<<dim3(16, 64), blk, 0, stream>>>(qbuf, wbuf, fc2b, out, nullptr, out, 8192, 2048, 8192);
}

// Round 4
// 1392.762 us; speedup vs baseline: 1.3063x; 1.0174x over previous
//
#include <hip/hip_runtime.h>
#include <hip/hip_bf16.h>
#include <cstdint>
#include <cstddef>

// Problem constants: S=2048, B=4, H=2048, NH=16, HD=128
#define TOK 8192      // S*B rows of the activation matrix
#define HDIM 2048
#define H3 6144       // 3*H

typedef float f32x4 __attribute__((ext_vector_type(4)));
typedef short bf16x8 __attribute__((ext_vector_type(8)));   // 8 bf16 in 4 VGPRs
typedef unsigned short u16;
typedef unsigned int u32;
typedef u32 u32x2 __attribute__((ext_vector_type(2)));
typedef u32 u32x4 __attribute__((ext_vector_type(4)));

__device__ __forceinline__ u16 f2bf(float f) {
  union { float f; u32 u; } v; v.f = f;
  u32 u = v.u;
  return (u16)((u + 0x7fffu + ((u >> 16) & 1u)) >> 16);   // RNE
}

__device__ __forceinline__ void gload16(const void* g, void* l) {
  // async global->LDS, 16B per lane; LDS dest is wave-uniform base + lane*16
  __builtin_amdgcn_global_load_lds((const __attribute__((address_space(1))) u32*)g,
                                   (__attribute__((address_space(3))) u32*)l, 16, 0, 0);
}

// ---------------- fp32 -> bf16 weight conversion ----------------
__global__ __launch_bounds__(256)
void cvt_kernel(const float* __restrict__ in, u16* __restrict__ out, int n4) {
  int i = blockIdx.x * 256 + threadIdx.x;
  if (i >= n4) return;
  float4 v = ((const float4*)in)[i];
  union { u16 o[4]; u32x2 d; } t;
  t.o[0] = f2bf(v.x); t.o[1] = f2bf(v.y); t.o[2] = f2bf(v.z); t.o[3] = f2bf(v.w);
  ((u32x2*)out)[i] = t.d;
}

// ---------------- LayerNorm (fp32 in, bf16 out), one row per block ----------------
__global__ __launch_bounds__(256)
void ln_kernel(const float* __restrict__ x, const float* __restrict__ g,
               const float* __restrict__ bta, u16* __restrict__ out) {
  const int row = blockIdx.x, tid = threadIdx.x;
  const int lane = tid & 63, w = tid >> 6;
  const float* xr = x + (size_t)row * HDIM + tid * 8;
  float4 a = *(const float4*)xr;
  float4 c = *(const float4*)(xr + 4);
  float s = a.x + a.y + a.z + a.w + c.x + c.y + c.z + c.w;
  float q = a.x*a.x + a.y*a.y + a.z*a.z + a.w*a.w + c.x*c.x + c.y*c.y + c.z*c.z + c.w*c.w;
#pragma unroll
  for (int m = 32; m >= 1; m >>= 1) { s += __shfl_xor(s, m, 64); q += __shfl_xor(q, m, 64); }
  __shared__ float red[8];
  if (lane == 0) { red[w] = s; red[4 + w] = q; }
  __syncthreads();
  s = red[0] + red[1] + red[2] + red[3];
  q = red[4] + red[5] + red[6] + red[7];
  const float mu = s * (1.0f / HDIM);
  const float rstd = rsqrtf(q * (1.0f / HDIM) - mu * mu + 1e-5f);
  const float* gp = g + tid * 8; const float* bp = bta + tid * 8;
  float4 g0 = *(const float4*)gp, g1 = *(const float4*)(gp + 4);
  float4 b0 = *(const float4*)bp, b1 = *(const float4*)(bp + 4);
  union { u16 o[8]; u32x4 d; } t;
  t.o[0] = f2bf((a.x - mu) * rstd * g0.x + b0.x);
  t.o[1] = f2bf((a.y - mu) * rstd * g0.y + b0.y);
  t.o[2] = f2bf((a.z - mu) * rstd * g0.z + b0.z);
  t.o[3] = f2bf((a.w - mu) * rstd * g0.w + b0.w);
  t.o[4] = f2bf((c.x - mu) * rstd * g1.x + b1.x);
  t.o[5] = f2bf((c.y - mu) * rstd * g1.y + b1.y);
  t.o[6] = f2bf((c.z - mu) * rstd * g1.z + b1.z);
  t.o[7] = f2bf((c.w - mu) * rstd * g1.w + b1.w);
  *(u32x4*)(out + (size_t)row * HDIM + tid * 8) = t.d;
}

// ---------------- GEMM 256x256 8-phase (T1+T2+T3+T4+T5) ----------------
// C[M,N] = A[M,K](bf16) @ B[N,K]^T(bf16) + bias
// EPI 0: bf16 out;  1: GELU(exact) -> bf16 out;  2: + resid(fp32) -> fp32 out
// 512 thr = 8 waves (2M x 4N); per-wave 128x64 out; BK=64; LDS 128 KiB 2-dbuf.
// Staging: 8 granules/tile (8KB each), order B0,B1,B2,B3,A0,A2,A1,A3, issued
// 2/phase for tile t+1 while computing tile t. Gates: vmcnt(4) end-p2
// (releases t's A1,A3), vmcnt(2) end-p4 (releases t+1's B*,A0,A2). Gate
// precedes barrier so all waves' loads are drained before any wave reads.
#define GBAR()  __builtin_amdgcn_s_barrier()
#define GLGK0() asm volatile("s_waitcnt lgkmcnt(0)" ::: "memory")
#define GVM(n)  asm volatile("s_waitcnt vmcnt(" #n ")" ::: "memory")

#define STAGE(o, g, tt) do {                                                   \
    const char* _src = ((o) ? gBb : gAb) + (size_t)(g) * 64 * rsK + (size_t)(tt) * 128; \
    char* _dst = Lb + ((((tt) & 1) << 16) + (o) * 32768 + (g) * 8192 + tid * 16); \
    gload16(_src, _dst);                                                       \
  } while (0)

#define PHASE_LOADS(qm, qn) do {                                               \
    _Pragma("unroll")                                                          \
    for (int mi4 = 0; mi4 < 4; ++mi4) {                                        \
      const int rowA = wm * 128 + (qm) * 64 + mi4 * 16 + l15;                  \
      _Pragma("unroll")                                                        \
      for (int ks = 0; ks < 2; ++ks)                                           \
        af[mi4][ks] = *(const bf16x8*)(Lb + bb + rowA * 128 + koff[ks]);       \
    }                                                                          \
    _Pragma("unroll")                                                          \
    for (int ni2 = 0; ni2 < 2; ++ni2) {                                        \
      const int rowB = wn * 64 + (qn) * 32 + ni2 * 16 + l15;                   \
      _Pragma("unroll")                                                        \
      for (int ks = 0; ks < 2; ++ks)                                           \
        bfv[ni2][ks] = *(const bf16x8*)(Lb + bb + 32768 + rowB * 128 + koff[ks]); \
    }                                                                          \
  } while (0)

#define PHASE_MFMA(qm, qn) do {                                                \
    __builtin_amdgcn_s_setprio(1);                                             \
    _Pragma("unroll")                                                          \
    for (int mi4 = 0; mi4 < 4; ++mi4)                                          \
      _Pragma("unroll")                                                        \
      for (int ni2 = 0; ni2 < 2; ++ni2)                                        \
        _Pragma("unroll")                                                      \
        for (int ks = 0; ks < 2; ++ks)                                         \
          acc[(qm) * 4 + mi4][(qn) * 2 + ni2] =                                \
            __builtin_amdgcn_mfma_f32_16x16x32_bf16(af[mi4][ks], bfv[ni2][ks], \
                acc[(qm) * 4 + mi4][(qn) * 2 + ni2], 0, 0, 0);                 \
    __builtin_amdgcn_s_setprio(0);                                             \
  } while (0)

template <int EPI>
__global__ __launch_bounds__(512, 2)
void gemm256(const u16* __restrict__ A, const u16* __restrict__ Bm,
             const float* __restrict__ bias, const float* __restrict__ resid,
             u16* __restrict__ Cb, float* __restrict__ Cf, int M, int N, int K) {
  __shared__ u16 lds[65536];               // 128 KiB
  char* Lb = (char*)lds;
  const int tid = threadIdx.x;
  const int lane = tid & 63, w = tid >> 6;
  const int wm = w >> 2, wn = w & 3;
  const int l15 = lane & 15, hi = lane >> 4;

  // T1: bijective XCD swizzle (all our grids have nwg % 8 == 0)
  const int gx = gridDim.x;
  const int nwg = gx * gridDim.y;
  int wgid = blockIdx.y * gx + blockIdx.x;
  wgid = (wgid & 7) * (nwg >> 3) + (wgid >> 3);
  const int tm = (wgid / gx) * 256, tn = (wgid % gx) * 256;

  const size_t rsK = (size_t)K * 2;        // global row stride (bytes)
  // staging: this thread's fixed (row-in-granule, swizzled col byte)
  const int sg_r = tid >> 3;
  const int sg_cb = ((tid & 7) * 16) ^ ((sg_r & 7) << 4);
  const char* gAb = (const char*)A + (size_t)(tm + sg_r) * rsK + sg_cb;
  const char* gBb = (const char*)Bm + (size_t)(tn + sg_r) * rsK + sg_cb;

  // ds_read swizzle: LDS slot s of row r holds global slot s ^ (r&7)
  const int swz = (l15 & 7) << 4;
  int koff[2];
#pragma unroll
  for (int ks = 0; ks < 2; ++ks) koff[ks] = (ks * 64 + hi * 16) ^ swz;

  f32x4 acc[8][4] = {};
  bf16x8 af[4][2], bfv[2][2];

  const int NT = K >> 6;                   // K-tiles of 64

  // prologue: stage tile 0, release all but its A1,A3
  STAGE(1, 0, 0); STAGE(1, 1, 0); STAGE(1, 2, 0); STAGE(1, 3, 0);
  STAGE(0, 0, 0); STAGE(0, 2, 0); STAGE(0, 1, 0); STAGE(0, 3, 0);
  GVM(2); GBAR();

  for (int t = 0; t < NT - 1; ++t) {
    const int bb = (t & 1) << 16;
    // P1: quadrant (0,0)
    PHASE_LOADS(0, 0);
    STAGE(1, 0, t + 1); STAGE(1, 1, t + 1);
    GBAR(); GLGK0(); PHASE_MFMA(0, 0); GBAR();
    // P2: quadrant (0,1)
    PHASE_LOADS(0, 1);
    STAGE(1, 2, t + 1); STAGE(1, 3, t + 1);
    GBAR(); GLGK0(); PHASE_MFMA(0, 1); GVM(4); GBAR();   // t's A1,A3 ready
    // P3: quadrant (1,0)
    PHASE_LOADS(1, 0);
    STAGE(0, 0, t + 1); STAGE(0, 2, t + 1);
    GBAR(); GLGK0(); PHASE_MFMA(1, 0); GBAR();
    // P4: quadrant (1,1)
    PHASE_LOADS(1, 1);
    STAGE(0, 1, t + 1); STAGE(0, 3, t + 1);
    GBAR(); GLGK0(); PHASE_MFMA(1, 1); GVM(2); GBAR();   // t+1's B*,A0,A2 ready
  }
  {                                        // last tile, no staging
    const int bb = ((NT - 1) & 1) << 16;
    PHASE_LOADS(0, 0);
    GBAR(); GLGK0(); PHASE_MFMA(0, 0); GBAR();
    PHASE_LOADS(0, 1);
    GBAR(); GLGK0(); PHASE_MFMA(0, 1); GVM(0); GBAR();   // drain A1,A3
    PHASE_LOADS(1, 0);
    GBAR(); GLGK0(); PHASE_MFMA(1, 0); GBAR();
    PHASE_LOADS(1, 1);
    GLGK0(); PHASE_MFMA(1, 1);
  }

  // epilogue
#pragma unroll
  for (int mi = 0; mi < 8; ++mi) {
#pragma unroll
    for (int ni = 0; ni < 4; ++ni) {
      const int col = tn + wn * 64 + ni * 16 + l15;
      const float bv = bias[col];
#pragma unroll
      for (int r = 0; r < 4; ++r) {
        const int row = tm + wm * 128 + mi * 16 + hi * 4 + r;
        float v = acc[mi][ni][r] + bv;
        if constexpr (EPI == 1) v = 0.5f * v * (1.0f + erff(v * 0.70710678118654752f));
        const size_t idx = (size_t)row * N + col;
        if constexpr (EPI == 2) Cf[idx] = v + resid[idx];
        else                    Cb[idx] = f2bf(v);
      }
    }
  }
}

// ---------------- V transpose: qkv V part -> Vt_g[bh][d][s] ----------------
__global__ __launch_bounds__(256)
void vtrans_kernel(const u16* __restrict__ qkv, u16* __restrict__ vt) {
  __shared__ u16 tile[32 * 136];
  const int s0 = blockIdx.x * 32;
  const int bh = blockIdx.y;
  const int b = bh >> 4, h = bh & 15;
  const int t = threadIdx.x;
  const int srow = t >> 3, scol = (t & 7) * 16;
  const u16* src = qkv + (size_t)((s0 + srow) * 4 + b) * H3 + 4096 + h * 128 + scol;
  *(bf16x8*)(tile + srow * 136 + scol)     = *(const bf16x8*)src;
  *(bf16x8*)(tile + srow * 136 + scol + 8) = *(const bf16x8*)(src + 8);
  __syncthreads();
  const int d = t >> 1, sc = (t & 1) * 16;
  union { u16 o[16]; u32x4 q[2]; } tmp;
#pragma unroll
  for (int i = 0; i < 16; ++i) tmp.o[i] = tile[(sc + i) * 136 + d];
  u16* dst = vt + ((size_t)bh * 128 + d) * 2048 + s0 + sc;
  *(u32x4*)dst       = tmp.q[0];
  *(u32x4*)(dst + 8) = tmp.q[1];
}

// ---------------- Flash attention (causal, 16 heads, HD=128) ----------------
__global__ __launch_bounds__(256, 2)
void attn_kernel(const u16* __restrict__ qkv, const u16* __restrict__ vt,
                 u16* __restrict__ outb) {
  const int qt = 31 - blockIdx.x;          // long blocks dispatch first
  const int bh = blockIdx.y;
  const int b = bh >> 4, h = bh & 15;
  const int tid = threadIdx.x, lane = tid & 63, w = tid >> 6;
  const int hi = lane >> 4, l15 = lane & 15;
  const int qs = qt * 64;

  __shared__ u16 Klds[64 * 128];           // [kv][d], rows 256B, swizzled
  __shared__ u16 Vlds[128 * 64];           // [d][kv], rows 128B, swizzled
  __shared__ u16 Plds[4 * 16 * 64];        // per-wave [16 q][64 kv], swizzled

  bf16x8 qf[4];
  {
    const int qrow = qs + w * 16 + l15;
    const u16* qp = qkv + (size_t)(qrow * 4 + b) * H3 + h * 128 + hi * 8;
#pragma unroll
    for (int kc = 0; kc < 4; ++kc) qf[kc] = *(const bf16x8*)(qp + kc * 32);
  }

  f32x4 o[8] = {};
  float mrun[4], lrun[4];
#pragma unroll
  for (int r = 0; r < 4; ++r) { mrun[r] = -1e30f; lrun[r] = 0.0f; }

  const float sc = 0.08838834764831845f;   // 1/sqrt(128)
  char* plb = (char*)(Plds + w * 1024);

  const int krow = tid >> 2;               // 0..63 kv row
  const int kcb  = (tid & 3) * 64;         // byte col in K row
  const int vd   = tid >> 1;               // 0..127 d row
  const int vhb  = (tid & 1) * 64;         // byte col in Vt row

  const int ntiles = qt + 1;
  for (int kt = 0; kt < ntiles; ++kt) {
    const int kv0 = kt * 64;
    const u16* ksrc = qkv + (size_t)((kv0 + krow) * 4 + b) * H3 + 2048 + h * 128 + kcb / 2;
    const u16* vsrc = vt + ((size_t)bh * 128 + vd) * 2048 + kv0 + (tid & 1) * 32;
    bf16x8 kr[4], vr[4];
#pragma unroll
    for (int c = 0; c < 4; ++c) { kr[c] = *(const bf16x8*)(ksrc + c * 8); vr[c] = *(const bf16x8*)(vsrc + c * 8); }

    __syncthreads();
#pragma unroll
    for (int c = 0; c < 4; ++c) {
      *(bf16x8*)((char*)Klds + ((krow * 256 + kcb + c * 16) ^ ((krow & 7) << 4))) = kr[c];
      *(bf16x8*)((char*)Vlds + ((vd * 128 + vhb + c * 16) ^ ((vd & 7) << 4)))     = vr[c];
    }
    __syncthreads();

    f32x4 s[4] = {};
#pragma unroll
    for (int kc = 0; kc < 4; ++kc) {
      const int dbyte = kc * 64 + hi * 16;
#pragma unroll
      for (int g = 0; g < 4; ++g) {
        const int row = g * 16 + l15;
        bf16x8 kf = *(const bf16x8*)((char*)Klds + ((row * 256 + dbyte) ^ ((l15 & 7) << 4)));
        s[g] = __builtin_amdgcn_mfma_f32_16x16x32_bf16(qf[kc], kf, s[g], 0, 0, 0);
      }
    }
#pragma unroll
    for (int g = 0; g < 4; ++g)
#pragma unroll
      for (int r = 0; r < 4; ++r) s[g][r] *= sc;

    if (kt == qt) {
#pragma unroll
      for (int g = 0; g < 4; ++g)
#pragma unroll
        for (int r = 0; r < 4; ++r) {
          const int qrel = w * 16 + hi * 4 + r;
          if (g * 16 + l15 > qrel) s[g][r] = -1e30f;
        }
    }

    float pm[4];
#pragma unroll
    for (int r = 0; r < 4; ++r)
      pm[r] = fmaxf(fmaxf(s[0][r], s[1][r]), fmaxf(s[2][r], s[3][r]));
#pragma unroll
    for (int m = 8; m >= 1; m >>= 1)
#pragma unroll
      for (int r = 0; r < 4; ++r) pm[r] = fmaxf(pm[r], __shfl_xor(pm[r], m, 64));

    float corr[4], rs[4];
    float p[4][4];
#pragma unroll
    for (int r = 0; r < 4; ++r) {
      const float mnew = fmaxf(mrun[r], pm[r]);
      corr[r] = __expf(mrun[r] - mnew);
      mrun[r] = mnew;
      rs[r] = 0.0f;
    }
#pragma unroll
    for (int g = 0; g < 4; ++g)
#pragma unroll
      for (int r = 0; r < 4; ++r) { p[g][r] = __expf(s[g][r] - mrun[r]); rs[r] += p[g][r]; }
#pragma unroll
    for (int m = 8; m >= 1; m >>= 1)
#pragma unroll
      for (int r = 0; r < 4; ++r) rs[r] += __shfl_xor(rs[r], m, 64);
#pragma unroll
    for (int r = 0; r < 4; ++r) lrun[r] = lrun[r] * corr[r] + rs[r];
#pragma unroll
    for (int nf = 0; nf < 8; ++nf)
#pragma unroll
      for (int r = 0; r < 4; ++r) o[nf][r] *= corr[r];

#pragma unroll
    for (int r = 0; r < 4; ++r) {
      const int prow = hi * 4 + r;
      const int sw = (prow & 7) << 4;
#pragma unroll
      for (int g = 0; g < 4; ++g)
        *(u16*)(plb + ((prow * 128 + (g * 16 + l15) * 2) ^ sw)) = f2bf(p[g][r]);
    }
    asm volatile("s_waitcnt lgkmcnt(0)" ::: "memory");
    bf16x8 pf[2];
#pragma unroll
    for (int hk = 0; hk < 2; ++hk)
      pf[hk] = *(const bf16x8*)(plb + ((l15 * 128 + hk * 64 + hi * 16) ^ ((l15 & 7) << 4)));

#pragma unroll
    for (int hk = 0; hk < 2; ++hk)
#pragma unroll
      for (int nf = 0; nf < 8; ++nf) {
        bf16x8 vf = *(const bf16x8*)((char*)Vlds +
                      (((nf * 16 + l15) * 128 + hk * 64 + hi * 16) ^ ((l15 & 7) << 4)));
        o[nf] = __builtin_amdgcn_mfma_f32_16x16x32_bf16(pf[hk], vf, o[nf], 0, 0, 0);
      }
  }

  float inv[4];
#pragma unroll
  for (int r = 0; r < 4; ++r) inv[r] = 1.0f / lrun[r];
#pragma unroll
  for (int nf = 0; nf < 8; ++nf) {
#pragma unroll
    for (int r = 0; r < 4; ++r) {
      const int rl = hi * 4 + r;
      const int t = (qs + w * 16 + rl) * 4 + b;
      outb[(size_t)t * HDIM + h * 128 + nf * 16 + l15] = f2bf(o[nf][r] * inv[r]);
    }
  }
}

// ---------------- launcher ----------------
extern "C" void kernel_launch(void* const* d_in, const int* in_sizes, int n_in,
                              void* d_out, int out_size, void* d_ws, size_t ws_size,
                              hipStream_t stream) {
  const float* x     = (const float*)d_in[0];
  const float* ln1g  = (const float*)d_in[1];
  const float* ln1b  = (const float*)d_in[2];
  const float* qkvw  = (const float*)d_in[3];
  const float* qkvb  = (const float*)d_in[4];
  const float* projw = (const float*)d_in[5];
  const float* projb = (const float*)d_in[6];
  const float* ln2g  = (const float*)d_in[7];
  const float* ln2b  = (const float*)d_in[8];
  const float* fc1w  = (const float*)d_in[9];
  const float* fc1b  = (const float*)d_in[10];
  const float* fc2w  = (const float*)d_in[11];
  const float* fc2b  = (const float*)d_in[12];
  float* out = (float*)d_out;

  // ws layout (192 MiB):
  //   [0,32M)    wbuf (weights bf16)             -- dead during attention
  //   [32M,64M)  pbuf (LN outputs bf16)          -- dead during attention
  //   [0,64M)    vtg  (V transposed, attn-only)  -- overlaps wbuf+pbuf
  //   [64M,192M) qbuf (qkv / fc1 out bf16)
  //   [160M,192M) aout (attn out, dead region of qbuf during attn)
  u16* wbuf = (u16*)d_ws;
  u16* pbuf = (u16*)((char*)d_ws + (size_t)32 * 1024 * 1024);
  u16* qbuf = (u16*)((char*)d_ws + (size_t)64 * 1024 * 1024);
  u16* vtg  = (u16*)d_ws;
  u16* aout = (u16*)((char*)d_ws + (size_t)160 * 1024 * 1024);

  dim3 blk(256);
  dim3 gblk(512);

  // LN1 -> pbuf (bf16)
  ln_kernel<<<8192, blk, 0, stream>>>(x, ln1g, ln1b, pbuf);
  // qkv_w -> bf16
  cvt_kernel<<<12288, blk, 0, stream>>>(qkvw, wbuf, 3145728);
  // qkv = h @ qkv_w^T + b  -> qbuf [8192 x 6144] bf16   (grid 24x32 = 768 blocks)
  gemm256<0><<<dim3(24, 32), gblk, 0, stream>>>(pbuf, wbuf, qkvb, nullptr, qbuf, nullptr, 8192, 6144, 2048);
  // V -> Vt_g [bh][d][s]
  vtrans_kernel<<<dim3(64, 64), blk, 0, stream>>>(qbuf, vtg);
  // attention -> aout [8192 x 2048] bf16
  attn_kernel<<<dim3(32, 64), blk, 0, stream>>>(qbuf, vtg, aout);
  // proj_w -> bf16 (vtg dead now)
  cvt_kernel<<<4096, blk, 0, stream>>>(projw, wbuf, 1048576);
  // x2 = x + attn @ proj_w^T + b  -> d_out (fp32)   (grid 8x32 = 256)
  gemm256<2><<<dim3(8, 32), gblk, 0, stream>>>(aout, wbuf, projb, x, nullptr, out, 8192, 2048, 2048);
  // LN2 -> pbuf (bf16)
  ln_kernel<<<8192, blk, 0, stream>>>(out, ln2g, ln2b, pbuf);
  // fc1_w -> bf16
  cvt_kernel<<<16384, blk, 0, stream>>>(fc1w, wbuf, 4194304);
  // h = gelu(ln2 @ fc1_w^T + b) -> qbuf [8192 x 8192] bf16   (grid 32x32 = 1024)
  gemm256<1><<<dim3(32, 32), gblk, 0, stream>>>(pbuf, wbuf, fc1b, nullptr, qbuf, nullptr, 8192, 8192, 2048);
  // fc2_w -> bf16
  cvt_kernel<<<16384, blk, 0, stream>>>(fc2w, wbuf, 4194304);
  // out = x2 + h @ fc2_w^T + b  (in-place residual on d_out)   (grid 8x32, K=8192)
  gemm256<2><<<dim3(8, 32), gblk, 0, stream>>>(qbuf, wbuf, fc2b, out, nullptr, out, 8192, 2048, 8192);
}

// Round 5
// 1371.141 us; speedup vs baseline: 1.3269x; 1.0158x over previous
//
#include <hip/hip_runtime.h>
#include <hip/hip_bf16.h>
#include <cstdint>
#include <cstddef>

// Problem constants: S=2048, B=4, H=2048, NH=16, HD=128
#define TOK 8192      // S*B rows of the activation matrix
#define HDIM 2048
#define H3 6144       // 3*H

typedef float f32x4 __attribute__((ext_vector_type(4)));
typedef short bf16x8 __attribute__((ext_vector_type(8)));   // 8 bf16 in 4 VGPRs
typedef unsigned short u16;
typedef unsigned int u32;
typedef u32 u32x2 __attribute__((ext_vector_type(2)));
typedef u32 u32x4 __attribute__((ext_vector_type(4)));

__device__ __forceinline__ u16 f2bf(float f) {
  union { float f; u32 u; } v; v.f = f;
  u32 u = v.u;
  return (u16)((u + 0x7fffu + ((u >> 16) & 1u)) >> 16);   // RNE
}

__device__ __forceinline__ void gload16(const void* g, void* l) {
  // async global->LDS, 16B per lane; LDS dest is wave-uniform base + lane*16
  __builtin_amdgcn_global_load_lds((const __attribute__((address_space(1))) u32*)g,
                                   (__attribute__((address_space(3))) u32*)l, 16, 0, 0);
}

// ---------------- fp32 -> bf16 weight conversion ----------------
__global__ __launch_bounds__(256)
void cvt_kernel(const float* __restrict__ in, u16* __restrict__ out, int n4) {
  int i = blockIdx.x * 256 + threadIdx.x;
  if (i >= n4) return;
  float4 v = ((const float4*)in)[i];
  union { u16 o[4]; u32x2 d; } t;
  t.o[0] = f2bf(v.x); t.o[1] = f2bf(v.y); t.o[2] = f2bf(v.z); t.o[3] = f2bf(v.w);
  ((u32x2*)out)[i] = t.d;
}

// ---------------- LayerNorm (fp32 in, bf16 out), one row per block ----------------
__global__ __launch_bounds__(256)
void ln_kernel(const float* __restrict__ x, const float* __restrict__ g,
               const float* __restrict__ bta, u16* __restrict__ out) {
  const int row = blockIdx.x, tid = threadIdx.x;
  const int lane = tid & 63, w = tid >> 6;
  const float* xr = x + (size_t)row * HDIM + tid * 8;
  float4 a = *(const float4*)xr;
  float4 c = *(const float4*)(xr + 4);
  float s = a.x + a.y + a.z + a.w + c.x + c.y + c.z + c.w;
  float q = a.x*a.x + a.y*a.y + a.z*a.z + a.w*a.w + c.x*c.x + c.y*c.y + c.z*c.z + c.w*c.w;
#pragma unroll
  for (int m = 32; m >= 1; m >>= 1) { s += __shfl_xor(s, m, 64); q += __shfl_xor(q, m, 64); }
  __shared__ float red[8];
  if (lane == 0) { red[w] = s; red[4 + w] = q; }
  __syncthreads();
  s = red[0] + red[1] + red[2] + red[3];
  q = red[4] + red[5] + red[6] + red[7];
  const float mu = s * (1.0f / HDIM);
  const float rstd = rsqrtf(q * (1.0f / HDIM) - mu * mu + 1e-5f);
  const float* gp = g + tid * 8; const float* bp = bta + tid * 8;
  float4 g0 = *(const float4*)gp, g1 = *(const float4*)(gp + 4);
  float4 b0 = *(const float4*)bp, b1 = *(const float4*)(bp + 4);
  union { u16 o[8]; u32x4 d; } t;
  t.o[0] = f2bf((a.x - mu) * rstd * g0.x + b0.x);
  t.o[1] = f2bf((a.y - mu) * rstd * g0.y + b0.y);
  t.o[2] = f2bf((a.z - mu) * rstd * g0.z + b0.z);
  t.o[3] = f2bf((a.w - mu) * rstd * g0.w + b0.w);
  t.o[4] = f2bf((c.x - mu) * rstd * g1.x + b1.x);
  t.o[5] = f2bf((c.y - mu) * rstd * g1.y + b1.y);
  t.o[6] = f2bf((c.z - mu) * rstd * g1.z + b1.z);
  t.o[7] = f2bf((c.w - mu) * rstd * g1.w + b1.w);
  *(u32x4*)(out + (size_t)row * HDIM + tid * 8) = t.d;
}

// ---------------- GEMM 256x256, BK=32, 4-slot LDS ring, counted vmcnt ----------
// C[M,N] = A[M,K](bf16) @ B[N,K]^T(bf16) + bias
// EPI 0: bf16 out;  1: GELU(exact) -> bf16 out;  2: + resid(fp32) -> fp32 out
// 512 thr = 8 waves (2M x 4N); per-wave 128x64 out.
// LDS: 4 slots x 32KB (A 2x8KB granules + B 2x8KB). Row stride 64B -> a
// 16-row fragment read is one contiguous 1KB block = 2 lanes/bank (free),
// so no swizzle is needed anywhere and staging is fully linear.
// Pipeline: prefetch depth 3 (slots t+1..t+3 in flight). Per K-tile:
//   gate vmcnt(8) [= 2 newer groups x 4 loads] -> tile t's group retired;
//   barrier (makes all waves' t-granules visible);
//   stage tile t+3; 12x ds_read_b128; 32x MFMA; lgkmcnt(0) [WAR: reads done
//   before next barrier lets anyone overwrite this slot's predecessor].
#define GBAR()  __builtin_amdgcn_s_barrier()
#define GLGK0() asm volatile("s_waitcnt lgkmcnt(0)" ::: "memory")
#define GVM(n)  asm volatile("s_waitcnt vmcnt(" #n ")" ::: "memory")

template <int EPI>
__global__ __launch_bounds__(512, 1)
void gemm256(const u16* __restrict__ A, const u16* __restrict__ Bm,
             const float* __restrict__ bias, const float* __restrict__ resid,
             u16* __restrict__ Cb, float* __restrict__ Cf, int M, int N, int K) {
  __shared__ u16 lds[65536];               // 128 KiB = 4 ring slots
  char* Lb = (char*)lds;
  const int tid = threadIdx.x;
  const int lane = tid & 63, w = tid >> 6;
  const int wm = w >> 2, wn = w & 3;
  const int l15 = lane & 15, hi = lane >> 4;

  // T1: bijective XCD swizzle (all our grids have nwg % 8 == 0)
  const int gx = gridDim.x;
  const int nwg = gx * gridDim.y;
  int wgid = blockIdx.y * gx + blockIdx.x;
  wgid = (wgid & 7) * (nwg >> 3) + (wgid >> 3);
  const int tm = (wgid / gx) * 256, tn = (wgid % gx) * 256;

  const size_t rsK = (size_t)K * 2;        // global row stride (bytes)
  const int sr  = tid >> 2;                // 0..127: row within granule
  const int scb = (tid & 3) * 16;          // byte col 0..48 (BK=32 -> 64B/row)
  const char* gA0 = (const char*)A + (size_t)(tm + sr) * rsK + scb;
  const char* gA1 = gA0 + (size_t)128 * rsK;
  const char* gB0 = (const char*)Bm + (size_t)(tn + sr) * rsK + scb;
  const char* gB1 = gB0 + (size_t)128 * rsK;

  const int NT = K >> 5;                   // K-tiles of 32

  // stage tile tt into ring slot tt&3 (4 x 8KB granules, linear)
#define STG(tt) do {                                              \
    char* _d = Lb + (((tt) & 3) * 32768 + tid * 16);              \
    const size_t _ko = (size_t)(tt) * 64;                         \
    gload16(gA0 + _ko, _d);                                       \
    gload16(gA1 + _ko, _d + 8192);                                \
    gload16(gB0 + _ko, _d + 16384);                               \
    gload16(gB1 + _ko, _d + 24576);                               \
  } while (0)

  f32x4 acc[8][4] = {};

  STG(0); STG(1); STG(2);                  // prefetch depth 3

  for (int t = 0; t < NT; ++t) {
    if (t < NT - 2)       GVM(8);          // allow t+1,t+2 groups in flight
    else if (t == NT - 2) GVM(4);          // tail peel
    else                  GVM(0);
    GBAR();                                // all waves' tile-t granules visible
    if (t + 3 < NT) STG(t + 3);

    const char* sb = Lb + (t & 3) * 32768;
    bf16x8 af[8], bf[4];
#pragma unroll
    for (int mi = 0; mi < 8; ++mi)
      af[mi] = *(const bf16x8*)(sb + wm * 8192 + (mi * 16 + l15) * 64 + hi * 16);
#pragma unroll
    for (int ni = 0; ni < 4; ++ni) {
      const int rowB = wn * 64 + ni * 16 + l15;
      bf[ni] = *(const bf16x8*)(sb + 16384 + (rowB >> 7) * 8192 + (rowB & 127) * 64 + hi * 16);
    }
    __builtin_amdgcn_s_setprio(1);
#pragma unroll
    for (int mi = 0; mi < 8; ++mi)
#pragma unroll
      for (int ni = 0; ni < 4; ++ni)
        acc[mi][ni] = __builtin_amdgcn_mfma_f32_16x16x32_bf16(af[mi], bf[ni], acc[mi][ni], 0, 0, 0);
    __builtin_amdgcn_s_setprio(0);
    GLGK0();                               // reads retired before next barrier
  }

  // epilogue
#pragma unroll
  for (int mi = 0; mi < 8; ++mi) {
#pragma unroll
    for (int ni = 0; ni < 4; ++ni) {
      const int col = tn + wn * 64 + ni * 16 + l15;
      const float bv = bias[col];
#pragma unroll
      for (int r = 0; r < 4; ++r) {
        const int row = tm + wm * 128 + mi * 16 + hi * 4 + r;
        float v = acc[mi][ni][r] + bv;
        if constexpr (EPI == 1) v = 0.5f * v * (1.0f + erff(v * 0.70710678118654752f));
        const size_t idx = (size_t)row * N + col;
        if constexpr (EPI == 2) Cf[idx] = v + resid[idx];
        else                    Cb[idx] = f2bf(v);
      }
    }
  }
#undef STG
}

// ---------------- V transpose: qkv V part -> Vt_g[bh][d][s] ----------------
__global__ __launch_bounds__(256)
void vtrans_kernel(const u16* __restrict__ qkv, u16* __restrict__ vt) {
  __shared__ u16 tile[32 * 136];
  const int s0 = blockIdx.x * 32;
  const int bh = blockIdx.y;
  const int b = bh >> 4, h = bh & 15;
  const int t = threadIdx.x;
  const int srow = t >> 3, scol = (t & 7) * 16;
  const u16* src = qkv + (size_t)((s0 + srow) * 4 + b) * H3 + 4096 + h * 128 + scol;
  *(bf16x8*)(tile + srow * 136 + scol)     = *(const bf16x8*)src;
  *(bf16x8*)(tile + srow * 136 + scol + 8) = *(const bf16x8*)(src + 8);
  __syncthreads();
  const int d = t >> 1, sc = (t & 1) * 16;
  union { u16 o[16]; u32x4 q[2]; } tmp;
#pragma unroll
  for (int i = 0; i < 16; ++i) tmp.o[i] = tile[(sc + i) * 136 + d];
  u16* dst = vt + ((size_t)bh * 128 + d) * 2048 + s0 + sc;
  *(u32x4*)dst       = tmp.q[0];
  *(u32x4*)(dst + 8) = tmp.q[1];
}

// ---------------- Flash attention (causal, 16 heads, HD=128) ----------------
__global__ __launch_bounds__(256, 2)
void attn_kernel(const u16* __restrict__ qkv, const u16* __restrict__ vt,
                 u16* __restrict__ outb) {
  const int qt = 31 - blockIdx.x;          // long blocks dispatch first
  const int bh = blockIdx.y;
  const int b = bh >> 4, h = bh & 15;
  const int tid = threadIdx.x, lane = tid & 63, w = tid >> 6;
  const int hi = lane >> 4, l15 = lane & 15;
  const int qs = qt * 64;

  __shared__ u16 Klds[64 * 128];           // [kv][d], rows 256B, swizzled
  __shared__ u16 Vlds[128 * 64];           // [d][kv], rows 128B, swizzled
  __shared__ u16 Plds[4 * 16 * 64];        // per-wave [16 q][64 kv], swizzled

  bf16x8 qf[4];
  {
    const int qrow = qs + w * 16 + l15;
    const u16* qp = qkv + (size_t)(qrow * 4 + b) * H3 + h * 128 + hi * 8;
#pragma unroll
    for (int kc = 0; kc < 4; ++kc) qf[kc] = *(const bf16x8*)(qp + kc * 32);
  }

  f32x4 o[8] = {};
  float mrun[4], lrun[4];
#pragma unroll
  for (int r = 0; r < 4; ++r) { mrun[r] = -1e30f; lrun[r] = 0.0f; }

  const float sc = 0.08838834764831845f;   // 1/sqrt(128)
  char* plb = (char*)(Plds + w * 1024);

  const int krow = tid >> 2;               // 0..63 kv row
  const int kcb  = (tid & 3) * 64;         // byte col in K row
  const int vd   = tid >> 1;               // 0..127 d row
  const int vhb  = (tid & 1) * 64;         // byte col in Vt row

  const int ntiles = qt + 1;
  for (int kt = 0; kt < ntiles; ++kt) {
    const int kv0 = kt * 64;
    const u16* ksrc = qkv + (size_t)((kv0 + krow) * 4 + b) * H3 + 2048 + h * 128 + kcb / 2;
    const u16* vsrc = vt + ((size_t)bh * 128 + vd) * 2048 + kv0 + (tid & 1) * 32;
    bf16x8 kr[4], vr[4];
#pragma unroll
    for (int c = 0; c < 4; ++c) { kr[c] = *(const bf16x8*)(ksrc + c * 8); vr[c] = *(const bf16x8*)(vsrc + c * 8); }

    __syncthreads();
#pragma unroll
    for (int c = 0; c < 4; ++c) {
      *(bf16x8*)((char*)Klds + ((krow * 256 + kcb + c * 16) ^ ((krow & 7) << 4))) = kr[c];
      *(bf16x8*)((char*)Vlds + ((vd * 128 + vhb + c * 16) ^ ((vd & 7) << 4)))     = vr[c];
    }
    __syncthreads();

    f32x4 s[4] = {};
#pragma unroll
    for (int kc = 0; kc < 4; ++kc) {
      const int dbyte = kc * 64 + hi * 16;
#pragma unroll
      for (int g = 0; g < 4; ++g) {
        const int row = g * 16 + l15;
        bf16x8 kf = *(const bf16x8*)((char*)Klds + ((row * 256 + dbyte) ^ ((l15 & 7) << 4)));
        s[g] = __builtin_amdgcn_mfma_f32_16x16x32_bf16(qf[kc], kf, s[g], 0, 0, 0);
      }
    }
#pragma unroll
    for (int g = 0; g < 4; ++g)
#pragma unroll
      for (int r = 0; r < 4; ++r) s[g][r] *= sc;

    if (kt == qt) {
#pragma unroll
      for (int g = 0; g < 4; ++g)
#pragma unroll
        for (int r = 0; r < 4; ++r) {
          const int qrel = w * 16 + hi * 4 + r;
          if (g * 16 + l15 > qrel) s[g][r] = -1e30f;
        }
    }

    float pm[4];
#pragma unroll
    for (int r = 0; r < 4; ++r)
      pm[r] = fmaxf(fmaxf(s[0][r], s[1][r]), fmaxf(s[2][r], s[3][r]));
#pragma unroll
    for (int m = 8; m >= 1; m >>= 1)
#pragma unroll
      for (int r = 0; r < 4; ++r) pm[r] = fmaxf(pm[r], __shfl_xor(pm[r], m, 64));

    float corr[4], rs[4];
    float p[4][4];
#pragma unroll
    for (int r = 0; r < 4; ++r) {
      const float mnew = fmaxf(mrun[r], pm[r]);
      corr[r] = __expf(mrun[r] - mnew);
      mrun[r] = mnew;
      rs[r] = 0.0f;
    }
#pragma unroll
    for (int g = 0; g < 4; ++g)
#pragma unroll
      for (int r = 0; r < 4; ++r) { p[g][r] = __expf(s[g][r] - mrun[r]); rs[r] += p[g][r]; }
#pragma unroll
    for (int m = 8; m >= 1; m >>= 1)
#pragma unroll
      for (int r = 0; r < 4; ++r) rs[r] += __shfl_xor(rs[r], m, 64);
#pragma unroll
    for (int r = 0; r < 4; ++r) lrun[r] = lrun[r] * corr[r] + rs[r];
#pragma unroll
    for (int nf = 0; nf < 8; ++nf)
#pragma unroll
      for (int r = 0; r < 4; ++r) o[nf][r] *= corr[r];

#pragma unroll
    for (int r = 0; r < 4; ++r) {
      const int prow = hi * 4 + r;
      const int sw = (prow & 7) << 4;
#pragma unroll
      for (int g = 0; g < 4; ++g)
        *(u16*)(plb + ((prow * 128 + (g * 16 + l15) * 2) ^ sw)) = f2bf(p[g][r]);
    }
    asm volatile("s_waitcnt lgkmcnt(0)" ::: "memory");
    bf16x8 pf[2];
#pragma unroll
    for (int hk = 0; hk < 2; ++hk)
      pf[hk] = *(const bf16x8*)(plb + ((l15 * 128 + hk * 64 + hi * 16) ^ ((l15 & 7) << 4)));

#pragma unroll
    for (int hk = 0; hk < 2; ++hk)
#pragma unroll
      for (int nf = 0; nf < 8; ++nf) {
        bf16x8 vf = *(const bf16x8*)((char*)Vlds +
                      (((nf * 16 + l15) * 128 + hk * 64 + hi * 16) ^ ((l15 & 7) << 4)));
        o[nf] = __builtin_amdgcn_mfma_f32_16x16x32_bf16(pf[hk], vf, o[nf], 0, 0, 0);
      }
  }

  float inv[4];
#pragma unroll
  for (int r = 0; r < 4; ++r) inv[r] = 1.0f / lrun[r];
#pragma unroll
  for (int nf = 0; nf < 8; ++nf) {
#pragma unroll
    for (int r = 0; r < 4; ++r) {
      const int rl = hi * 4 + r;
      const int t = (qs + w * 16 + rl) * 4 + b;
      outb[(size_t)t * HDIM + h * 128 + nf * 16 + l15] = f2bf(o[nf][r] * inv[r]);
    }
  }
}

// ---------------- launcher ----------------
extern "C" void kernel_launch(void* const* d_in, const int* in_sizes, int n_in,
                              void* d_out, int out_size, void* d_ws, size_t ws_size,
                              hipStream_t stream) {
  const float* x     = (const float*)d_in[0];
  const float* ln1g  = (const float*)d_in[1];
  const float* ln1b  = (const float*)d_in[2];
  const float* qkvw  = (const float*)d_in[3];
  const float* qkvb  = (const float*)d_in[4];
  const float* projw = (const float*)d_in[5];
  const float* projb = (const float*)d_in[6];
  const float* ln2g  = (const float*)d_in[7];
  const float* ln2b  = (const float*)d_in[8];
  const float* fc1w  = (const float*)d_in[9];
  const float* fc1b  = (const float*)d_in[10];
  const float* fc2w  = (const float*)d_in[11];
  const float* fc2b  = (const float*)d_in[12];
  float* out = (float*)d_out;

  // ws layout (192 MiB):
  //   [0,32M)    wbuf (weights bf16)             -- dead during attention
  //   [32M,64M)  pbuf (LN outputs bf16)          -- dead during attention
  //   [0,64M)    vtg  (V transposed, attn-only)  -- overlaps wbuf+pbuf
  //   [64M,192M) qbuf (qkv / fc1 out bf16)
  //   [160M,192M) aout (attn out, dead region of qbuf during attn)
  u16* wbuf = (u16*)d_ws;
  u16* pbuf = (u16*)((char*)d_ws + (size_t)32 * 1024 * 1024);
  u16* qbuf = (u16*)((char*)d_ws + (size_t)64 * 1024 * 1024);
  u16* vtg  = (u16*)d_ws;
  u16* aout = (u16*)((char*)d_ws + (size_t)160 * 1024 * 1024);

  dim3 blk(256);
  dim3 gblk(512);

  // LN1 -> pbuf (bf16)
  ln_kernel<<<8192, blk, 0, stream>>>(x, ln1g, ln1b, pbuf);
  // qkv_w -> bf16
  cvt_kernel<<<12288, blk, 0, stream>>>(qkvw, wbuf, 3145728);
  // qkv = h @ qkv_w^T + b  -> qbuf [8192 x 6144] bf16   (grid 24x32 = 768 blocks)
  gemm256<0><<<dim3(24, 32), gblk, 0, stream>>>(pbuf, wbuf, qkvb, nullptr, qbuf, nullptr, 8192, 6144, 2048);
  // V -> Vt_g [bh][d][s]
  vtrans_kernel<<<dim3(64, 64), blk, 0, stream>>>(qbuf, vtg);
  // attention -> aout [8192 x 2048] bf16
  attn_kernel<<<dim3(32, 64), blk, 0, stream>>>(qbuf, vtg, aout);
  // proj_w -> bf16 (vtg dead now)
  cvt_kernel<<<4096, blk, 0, stream>>>(projw, wbuf, 1048576);
  // x2 = x + attn @ proj_w^T + b  -> d_out (fp32)   (grid 8x32 = 256)
  gemm256<2><<<dim3(8, 32), gblk, 0, stream>>>(aout, wbuf, projb, x, nullptr, out, 8192, 2048, 2048);
  // LN2 -> pbuf (bf16)
  ln_kernel<<<8192, blk, 0, stream>>>(out, ln2g, ln2b, pbuf);
  // fc1_w -> bf16
  cvt_kernel<<<16384, blk, 0, stream>>>(fc1w, wbuf, 4194304);
  // h = gelu(ln2 @ fc1_w^T + b) -> qbuf [8192 x 8192] bf16   (grid 32x32 = 1024)
  gemm256<1><<<dim3(32, 32), gblk, 0, stream>>>(pbuf, wbuf, fc1b, nullptr, qbuf, nullptr, 8192, 8192, 2048);
  // fc2_w -> bf16
  cvt_kernel<<<16384, blk, 0, stream>>>(fc2w, wbuf, 4194304);
  // out = x2 + h @ fc2_w^T + b  (in-place residual on d_out)   (grid 8x32, K=8192)
  gemm256<2><<<dim3(8, 32), gblk, 0, stream>>>(qbuf, wbuf, fc2b, out, nullptr, out, 8192, 2048, 8192);
}

// Round 6
// 1339.439 us; speedup vs baseline: 1.3583x; 1.0237x over previous
//
#include <hip/hip_runtime.h>
#include <hip/hip_bf16.h>
#include <cstdint>
#include <cstddef>

// Problem constants: S=2048, B=4, H=2048, NH=16, HD=128
#define TOK 8192      // S*B rows of the activation matrix
#define HDIM 2048
#define H3 6144       // 3*H

typedef float f32x4 __attribute__((ext_vector_type(4)));
typedef short bf16x8 __attribute__((ext_vector_type(8)));   // 8 bf16 in 4 VGPRs
typedef unsigned short u16;
typedef unsigned int u32;
typedef u32 u32x2 __attribute__((ext_vector_type(2)));
typedef u32 u32x4 __attribute__((ext_vector_type(4)));

__device__ __forceinline__ u16 f2bf(float f) {
  union { float f; u32 u; } v; v.f = f;
  u32 u = v.u;
  return (u16)((u + 0x7fffu + ((u >> 16) & 1u)) >> 16);   // RNE
}

__device__ __forceinline__ void gload16(const void* g, void* l) {
  // async global->LDS, 16B per lane; LDS dest is wave-uniform base + lane*16
  __builtin_amdgcn_global_load_lds((const __attribute__((address_space(1))) u32*)g,
                                   (__attribute__((address_space(3))) u32*)l, 16, 0, 0);
}

// ---------------- fp32 -> bf16 weight conversion ----------------
__global__ __launch_bounds__(256)
void cvt_kernel(const float* __restrict__ in, u16* __restrict__ out, int n4) {
  int i = blockIdx.x * 256 + threadIdx.x;
  if (i >= n4) return;
  float4 v = ((const float4*)in)[i];
  union { u16 o[4]; u32x2 d; } t;
  t.o[0] = f2bf(v.x); t.o[1] = f2bf(v.y); t.o[2] = f2bf(v.z); t.o[3] = f2bf(v.w);
  ((u32x2*)out)[i] = t.d;
}

// ---------------- LayerNorm (fp32 in, bf16 out), one row per block ----------------
__global__ __launch_bounds__(256)
void ln_kernel(const float* __restrict__ x, const float* __restrict__ g,
               const float* __restrict__ bta, u16* __restrict__ out) {
  const int row = blockIdx.x, tid = threadIdx.x;
  const int lane = tid & 63, w = tid >> 6;
  const float* xr = x + (size_t)row * HDIM + tid * 8;
  float4 a = *(const float4*)xr;
  float4 c = *(const float4*)(xr + 4);
  float s = a.x + a.y + a.z + a.w + c.x + c.y + c.z + c.w;
  float q = a.x*a.x + a.y*a.y + a.z*a.z + a.w*a.w + c.x*c.x + c.y*c.y + c.z*c.z + c.w*c.w;
#pragma unroll
  for (int m = 32; m >= 1; m >>= 1) { s += __shfl_xor(s, m, 64); q += __shfl_xor(q, m, 64); }
  __shared__ float red[8];
  if (lane == 0) { red[w] = s; red[4 + w] = q; }
  __syncthreads();
  s = red[0] + red[1] + red[2] + red[3];
  q = red[4] + red[5] + red[6] + red[7];
  const float mu = s * (1.0f / HDIM);
  const float rstd = rsqrtf(q * (1.0f / HDIM) - mu * mu + 1e-5f);
  const float* gp = g + tid * 8; const float* bp = bta + tid * 8;
  float4 g0 = *(const float4*)gp, g1 = *(const float4*)(gp + 4);
  float4 b0 = *(const float4*)bp, b1 = *(const float4*)(bp + 4);
  union { u16 o[8]; u32x4 d; } t;
  t.o[0] = f2bf((a.x - mu) * rstd * g0.x + b0.x);
  t.o[1] = f2bf((a.y - mu) * rstd * g0.y + b0.y);
  t.o[2] = f2bf((a.z - mu) * rstd * g0.z + b0.z);
  t.o[3] = f2bf((a.w - mu) * rstd * g0.w + b0.w);
  t.o[4] = f2bf((c.x - mu) * rstd * g1.x + b1.x);
  t.o[5] = f2bf((c.y - mu) * rstd * g1.y + b1.y);
  t.o[6] = f2bf((c.z - mu) * rstd * g1.z + b1.z);
  t.o[7] = f2bf((c.w - mu) * rstd * g1.w + b1.w);
  *(u32x4*)(out + (size_t)row * HDIM + tid * 8) = t.d;
}

// ---------------- GEMM 256x256, BK=32, 4-slot LDS ring, counted vmcnt ----------
// C[M,N] = A[M,K](bf16) @ B[N,K]^T(bf16) + bias
// EPI 0: bf16 out;  1: GELU(exact) -> bf16 out;  2: + resid(fp32) -> fp32 out
// 512 thr = 8 waves (2M x 4N); per-wave 128x64 out.
// LDS: 4 ring slots x 32KB (A 2x8KB granules + B 2x8KB), 64B rows.
// SLOT SWIZZLE (fixes r5's 8-way conflict): physical 16B slot within a row
//   s' = s ^ ((row>>1)&3). Read side: s' = hi ^ ((l15>>1)&3) (per-thread
//   const; mi/ni/wn drop out mod 4) -> each 16-lane group covers all 8
//   bank-groups exactly 2x = conflict-free (2-way is free, m136).
// Write side (rule 21): gload_lds dest linear; global SOURCE col pre-swizzled
//   with the same XOR involution.
// Pipeline: prefetch depth 3; per K-tile: gate vmcnt(8) [2 newer groups x 4
//   loads] -> tile t retired; barrier; stage t+3; 12x ds_read_b128; 32 MFMA;
//   lgkmcnt(0) before next barrier (WAR on ring slot).
#define GBAR()  __builtin_amdgcn_s_barrier()
#define GLGK0() asm volatile("s_waitcnt lgkmcnt(0)" ::: "memory")
#define GVM(n)  asm volatile("s_waitcnt vmcnt(" #n ")" ::: "memory")

template <int EPI>
__global__ __launch_bounds__(512, 1)
void gemm256(const u16* __restrict__ A, const u16* __restrict__ Bm,
             const float* __restrict__ bias, const float* __restrict__ resid,
             u16* __restrict__ Cb, float* __restrict__ Cf, int M, int N, int K) {
  __shared__ u16 lds[65536];               // 128 KiB = 4 ring slots
  char* Lb = (char*)lds;
  const int tid = threadIdx.x;
  const int lane = tid & 63, w = tid >> 6;
  const int wm = w >> 2, wn = w & 3;
  const int l15 = lane & 15, hi = lane >> 4;

  // T1: bijective XCD swizzle (all our grids have nwg % 8 == 0)
  const int gx = gridDim.x;
  const int nwg = gx * gridDim.y;
  int wgid = blockIdx.y * gx + blockIdx.x;
  wgid = (wgid & 7) * (nwg >> 3) + (wgid >> 3);
  const int tm = (wgid / gx) * 256, tn = (wgid % gx) * 256;

  const size_t rsK = (size_t)K * 2;        // global row stride (bytes)
  const int sr  = tid >> 2;                // 0..127: row within granule
  // pre-swizzled source slot: s_log = s_lin ^ ((sr>>1)&3)
  const int scb = (((tid & 3) ^ ((tid >> 3) & 3)) * 16);
  const char* gA0 = (const char*)A + (size_t)(tm + sr) * rsK + scb;
  const char* gA1 = gA0 + (size_t)128 * rsK;
  const char* gB0 = (const char*)Bm + (size_t)(tn + sr) * rsK + scb;
  const char* gB1 = gB0 + (size_t)128 * rsK;

  const int NT = K >> 5;                   // K-tiles of 32

  // stage tile tt into ring slot tt&3 (4 x 8KB granules, linear dest)
#define STG(tt) do {                                              \
    char* _d = Lb + (((tt) & 3) * 32768 + tid * 16);              \
    const size_t _ko = (size_t)(tt) * 64;                         \
    gload16(gA0 + _ko, _d);                                       \
    gload16(gA1 + _ko, _d + 8192);                                \
    gload16(gB0 + _ko, _d + 16384);                               \
    gload16(gB1 + _ko, _d + 24576);                               \
  } while (0)

  f32x4 acc[8][4] = {};

  // swizzled 16B fragment slot within the 64B row (per-thread constant)
  const int fo = (hi ^ ((l15 >> 1) & 3)) * 16;

  STG(0); STG(1); STG(2);                  // prefetch depth 3

  for (int t = 0; t < NT; ++t) {
    if (t < NT - 2)       GVM(8);          // allow t+1,t+2 groups in flight
    else if (t == NT - 2) GVM(4);          // tail peel
    else                  GVM(0);
    GBAR();                                // all waves' tile-t granules visible
    if (t + 3 < NT) STG(t + 3);

    const char* sb = Lb + (t & 3) * 32768;
    bf16x8 af[8], bf[4];
#pragma unroll
    for (int mi = 0; mi < 8; ++mi)
      af[mi] = *(const bf16x8*)(sb + wm * 8192 + (mi * 16 + l15) * 64 + fo);
#pragma unroll
    for (int ni = 0; ni < 4; ++ni) {
      const int rowB = wn * 64 + ni * 16 + l15;
      bf[ni] = *(const bf16x8*)(sb + 16384 + (rowB >> 7) * 8192 + (rowB & 127) * 64 + fo);
    }
    __builtin_amdgcn_s_setprio(1);
#pragma unroll
    for (int mi = 0; mi < 8; ++mi)
#pragma unroll
      for (int ni = 0; ni < 4; ++ni)
        acc[mi][ni] = __builtin_amdgcn_mfma_f32_16x16x32_bf16(af[mi], bf[ni], acc[mi][ni], 0, 0, 0);
    __builtin_amdgcn_s_setprio(0);
    GLGK0();                               // reads retired before next barrier
  }

  // epilogue
#pragma unroll
  for (int mi = 0; mi < 8; ++mi) {
#pragma unroll
    for (int ni = 0; ni < 4; ++ni) {
      const int col = tn + wn * 64 + ni * 16 + l15;
      const float bv = bias[col];
#pragma unroll
      for (int r = 0; r < 4; ++r) {
        const int row = tm + wm * 128 + mi * 16 + hi * 4 + r;
        float v = acc[mi][ni][r] + bv;
        if constexpr (EPI == 1) v = 0.5f * v * (1.0f + erff(v * 0.70710678118654752f));
        const size_t idx = (size_t)row * N + col;
        if constexpr (EPI == 2) Cf[idx] = v + resid[idx];
        else                    Cb[idx] = f2bf(v);
      }
    }
  }
#undef STG
}

// ---------------- V transpose: qkv V part -> Vt_g[bh][d][s] ----------------
__global__ __launch_bounds__(256)
void vtrans_kernel(const u16* __restrict__ qkv, u16* __restrict__ vt) {
  __shared__ u16 tile[32 * 136];
  const int s0 = blockIdx.x * 32;
  const int bh = blockIdx.y;
  const int b = bh >> 4, h = bh & 15;
  const int t = threadIdx.x;
  const int srow = t >> 3, scol = (t & 7) * 16;
  const u16* src = qkv + (size_t)((s0 + srow) * 4 + b) * H3 + 4096 + h * 128 + scol;
  *(bf16x8*)(tile + srow * 136 + scol)     = *(const bf16x8*)src;
  *(bf16x8*)(tile + srow * 136 + scol + 8) = *(const bf16x8*)(src + 8);
  __syncthreads();
  const int d = t >> 1, sc = (t & 1) * 16;
  union { u16 o[16]; u32x4 q[2]; } tmp;
#pragma unroll
  for (int i = 0; i < 16; ++i) tmp.o[i] = tile[(sc + i) * 136 + d];
  u16* dst = vt + ((size_t)bh * 128 + d) * 2048 + s0 + sc;
  *(u32x4*)dst       = tmp.q[0];
  *(u32x4*)(dst + 8) = tmp.q[1];
}

// ---------------- Flash attention (causal, 16 heads, HD=128) ----------------
__global__ __launch_bounds__(256, 2)
void attn_kernel(const u16* __restrict__ qkv, const u16* __restrict__ vt,
                 u16* __restrict__ outb) {
  const int qt = 31 - blockIdx.x;          // long blocks dispatch first
  const int bh = blockIdx.y;
  const int b = bh >> 4, h = bh & 15;
  const int tid = threadIdx.x, lane = tid & 63, w = tid >> 6;
  const int hi = lane >> 4, l15 = lane & 15;
  const int qs = qt * 64;

  __shared__ u16 Klds[64 * 128];           // [kv][d], rows 256B, swizzled
  __shared__ u16 Vlds[128 * 64];           // [d][kv], rows 128B, swizzled
  __shared__ u16 Plds[4 * 16 * 64];        // per-wave [16 q][64 kv], swizzled

  bf16x8 qf[4];
  {
    const int qrow = qs + w * 16 + l15;
    const u16* qp = qkv + (size_t)(qrow * 4 + b) * H3 + h * 128 + hi * 8;
#pragma unroll
    for (int kc = 0; kc < 4; ++kc) qf[kc] = *(const bf16x8*)(qp + kc * 32);
  }

  f32x4 o[8] = {};
  float mrun[4], lrun[4];
#pragma unroll
  for (int r = 0; r < 4; ++r) { mrun[r] = -1e30f; lrun[r] = 0.0f; }

  const float sc = 0.08838834764831845f;   // 1/sqrt(128)
  char* plb = (char*)(Plds + w * 1024);

  const int krow = tid >> 2;               // 0..63 kv row
  const int kcb  = (tid & 3) * 64;         // byte col in K row
  const int vd   = tid >> 1;               // 0..127 d row
  const int vhb  = (tid & 1) * 64;         // byte col in Vt row

  const int ntiles = qt + 1;
  for (int kt = 0; kt < ntiles; ++kt) {
    const int kv0 = kt * 64;
    const u16* ksrc = qkv + (size_t)((kv0 + krow) * 4 + b) * H3 + 2048 + h * 128 + kcb / 2;
    const u16* vsrc = vt + ((size_t)bh * 128 + vd) * 2048 + kv0 + (tid & 1) * 32;
    bf16x8 kr[4], vr[4];
#pragma unroll
    for (int c = 0; c < 4; ++c) { kr[c] = *(const bf16x8*)(ksrc + c * 8); vr[c] = *(const bf16x8*)(vsrc + c * 8); }

    __syncthreads();
#pragma unroll
    for (int c = 0; c < 4; ++c) {
      *(bf16x8*)((char*)Klds + ((krow * 256 + kcb + c * 16) ^ ((krow & 7) << 4))) = kr[c];
      *(bf16x8*)((char*)Vlds + ((vd * 128 + vhb + c * 16) ^ ((vd & 7) << 4)))     = vr[c];
    }
    __syncthreads();

    f32x4 s[4] = {};
#pragma unroll
    for (int kc = 0; kc < 4; ++kc) {
      const int dbyte = kc * 64 + hi * 16;
#pragma unroll
      for (int g = 0; g < 4; ++g) {
        const int row = g * 16 + l15;
        bf16x8 kf = *(const bf16x8*)((char*)Klds + ((row * 256 + dbyte) ^ ((l15 & 7) << 4)));
        s[g] = __builtin_amdgcn_mfma_f32_16x16x32_bf16(qf[kc], kf, s[g], 0, 0, 0);
      }
    }
#pragma unroll
    for (int g = 0; g < 4; ++g)
#pragma unroll
      for (int r = 0; r < 4; ++r) s[g][r] *= sc;

    if (kt == qt) {
#pragma unroll
      for (int g = 0; g < 4; ++g)
#pragma unroll
        for (int r = 0; r < 4; ++r) {
          const int qrel = w * 16 + hi * 4 + r;
          if (g * 16 + l15 > qrel) s[g][r] = -1e30f;
        }
    }

    float pm[4];
#pragma unroll
    for (int r = 0; r < 4; ++r)
      pm[r] = fmaxf(fmaxf(s[0][r], s[1][r]), fmaxf(s[2][r], s[3][r]));
#pragma unroll
    for (int m = 8; m >= 1; m >>= 1)
#pragma unroll
      for (int r = 0; r < 4; ++r) pm[r] = fmaxf(pm[r], __shfl_xor(pm[r], m, 64));

    float corr[4], rs[4];
    float p[4][4];
#pragma unroll
    for (int r = 0; r < 4; ++r) {
      const float mnew = fmaxf(mrun[r], pm[r]);
      corr[r] = __expf(mrun[r] - mnew);
      mrun[r] = mnew;
      rs[r] = 0.0f;
    }
#pragma unroll
    for (int g = 0; g < 4; ++g)
#pragma unroll
      for (int r = 0; r < 4; ++r) { p[g][r] = __expf(s[g][r] - mrun[r]); rs[r] += p[g][r]; }
#pragma unroll
    for (int m = 8; m >= 1; m >>= 1)
#pragma unroll
      for (int r = 0; r < 4; ++r) rs[r] += __shfl_xor(rs[r], m, 64);
#pragma unroll
    for (int r = 0; r < 4; ++r) lrun[r] = lrun[r] * corr[r] + rs[r];
#pragma unroll
    for (int nf = 0; nf < 8; ++nf)
#pragma unroll
      for (int r = 0; r < 4; ++r) o[nf][r] *= corr[r];

#pragma unroll
    for (int r = 0; r < 4; ++r) {
      const int prow = hi * 4 + r;
      const int sw = (prow & 7) << 4;
#pragma unroll
      for (int g = 0; g < 4; ++g)
        *(u16*)(plb + ((prow * 128 + (g * 16 + l15) * 2) ^ sw)) = f2bf(p[g][r]);
    }
    asm volatile("s_waitcnt lgkmcnt(0)" ::: "memory");
    bf16x8 pf[2];
#pragma unroll
    for (int hk = 0; hk < 2; ++hk)
      pf[hk] = *(const bf16x8*)(plb + ((l15 * 128 + hk * 64 + hi * 16) ^ ((l15 & 7) << 4)));

#pragma unroll
    for (int hk = 0; hk < 2; ++hk)
#pragma unroll
      for (int nf = 0; nf < 8; ++nf) {
        bf16x8 vf = *(const bf16x8*)((char*)Vlds +
                      (((nf * 16 + l15) * 128 + hk * 64 + hi * 16) ^ ((l15 & 7) << 4)));
        o[nf] = __builtin_amdgcn_mfma_f32_16x16x32_bf16(pf[hk], vf, o[nf], 0, 0, 0);
      }
  }

  float inv[4];
#pragma unroll
  for (int r = 0; r < 4; ++r) inv[r] = 1.0f / lrun[r];
#pragma unroll
  for (int nf = 0; nf < 8; ++nf) {
#pragma unroll
    for (int r = 0; r < 4; ++r) {
      const int rl = hi * 4 + r;
      const int t = (qs + w * 16 + rl) * 4 + b;
      outb[(size_t)t * HDIM + h * 128 + nf * 16 + l15] = f2bf(o[nf][r] * inv[r]);
    }
  }
}

// ---------------- launcher ----------------
extern "C" void kernel_launch(void* const* d_in, const int* in_sizes, int n_in,
                              void* d_out, int out_size, void* d_ws, size_t ws_size,
                              hipStream_t stream) {
  const float* x     = (const float*)d_in[0];
  const float* ln1g  = (const float*)d_in[1];
  const float* ln1b  = (const float*)d_in[2];
  const float* qkvw  = (const float*)d_in[3];
  const float* qkvb  = (const float*)d_in[4];
  const float* projw = (const float*)d_in[5];
  const float* projb = (const float*)d_in[6];
  const float* ln2g  = (const float*)d_in[7];
  const float* ln2b  = (const float*)d_in[8];
  const float* fc1w  = (const float*)d_in[9];
  const float* fc1b  = (const float*)d_in[10];
  const float* fc2w  = (const float*)d_in[11];
  const float* fc2b  = (const float*)d_in[12];
  float* out = (float*)d_out;

  // ws layout (192 MiB):
  //   [0,32M)    wbuf (weights bf16)             -- dead during attention
  //   [32M,64M)  pbuf (LN outputs bf16)          -- dead during attention
  //   [0,64M)    vtg  (V transposed, attn-only)  -- overlaps wbuf+pbuf
  //   [64M,192M) qbuf (qkv / fc1 out bf16)
  //   [160M,192M) aout (attn out, dead region of qbuf during attn)
  u16* wbuf = (u16*)d_ws;
  u16* pbuf = (u16*)((char*)d_ws + (size_t)32 * 1024 * 1024);
  u16* qbuf = (u16*)((char*)d_ws + (size_t)64 * 1024 * 1024);
  u16* vtg  = (u16*)d_ws;
  u16* aout = (u16*)((char*)d_ws + (size_t)160 * 1024 * 1024);

  dim3 blk(256);
  dim3 gblk(512);

  // LN1 -> pbuf (bf16)
  ln_kernel<<<8192, blk, 0, stream>>>(x, ln1g, ln1b, pbuf);
  // qkv_w -> bf16
  cvt_kernel<<<12288, blk, 0, stream>>>(qkvw, wbuf, 3145728);
  // qkv = h @ qkv_w^T + b  -> qbuf [8192 x 6144] bf16   (grid 24x32 = 768 blocks)
  gemm256<0><<<dim3(24, 32), gblk, 0, stream>>>(pbuf, wbuf, qkvb, nullptr, qbuf, nullptr, 8192, 6144, 2048);
  // V -> Vt_g [bh][d][s]
  vtrans_kernel<<<dim3(64, 64), blk, 0, stream>>>(qbuf, vtg);
  // attention -> aout [8192 x 2048] bf16
  attn_kernel<<<dim3(32, 64), blk, 0, stream>>>(qbuf, vtg, aout);
  // proj_w -> bf16 (vtg dead now)
  cvt_kernel<<<4096, blk, 0, stream>>>(projw, wbuf, 1048576);
  // x2 = x + attn @ proj_w^T + b  -> d_out (fp32)   (grid 8x32 = 256)
  gemm256<2><<<dim3(8, 32), gblk, 0, stream>>>(aout, wbuf, projb, x, nullptr, out, 8192, 2048, 2048);
  // LN2 -> pbuf (bf16)
  ln_kernel<<<8192, blk, 0, stream>>>(out, ln2g, ln2b, pbuf);
  // fc1_w -> bf16
  cvt_kernel<<<16384, blk, 0, stream>>>(fc1w, wbuf, 4194304);
  // h = gelu(ln2 @ fc1_w^T + b) -> qbuf [8192 x 8192] bf16   (grid 32x32 = 1024)
  gemm256<1><<<dim3(32, 32), gblk, 0, stream>>>(pbuf, wbuf, fc1b, nullptr, qbuf, nullptr, 8192, 8192, 2048);
  // fc2_w -> bf16
  cvt_kernel<<<16384, blk, 0, stream>>>(fc2w, wbuf, 4194304);
  // out = x2 + h @ fc2_w^T + b  (in-place residual on d_out)   (grid 8x32, K=8192)
  gemm256<2><<<dim3(8, 32), gblk, 0, stream>>>(qbuf, wbuf, fc2b, out, nullptr, out, 8192, 2048, 8192);
}

// Round 7
// 1315.356 us; speedup vs baseline: 1.3832x; 1.0183x over previous
//
#include <hip/hip_runtime.h>
#include <hip/hip_bf16.h>
#include <cstdint>
#include <cstddef>

// Problem constants: S=2048, B=4, H=2048, NH=16, HD=128
#define TOK 8192      // S*B rows of the activation matrix
#define HDIM 2048
#define H3 6144       // 3*H

typedef float f32x4 __attribute__((ext_vector_type(4)));
typedef short bf16x8 __attribute__((ext_vector_type(8)));   // 8 bf16 in 4 VGPRs
typedef unsigned short u16;
typedef unsigned int u32;
typedef u32 u32x2 __attribute__((ext_vector_type(2)));
typedef u32 u32x4 __attribute__((ext_vector_type(4)));

__device__ __forceinline__ u16 f2bf(float f) {
  union { float f; u32 u; } v; v.f = f;
  u32 u = v.u;
  return (u16)((u + 0x7fffu + ((u >> 16) & 1u)) >> 16);   // RNE
}

__device__ __forceinline__ void gload16(const void* g, void* l) {
  // async global->LDS, 16B per lane; LDS dest is wave-uniform base + lane*16
  __builtin_amdgcn_global_load_lds((const __attribute__((address_space(1))) u32*)g,
                                   (__attribute__((address_space(3))) u32*)l, 16, 0, 0);
}

// ---------------- fp32 -> bf16 weight conversion ----------------
__global__ __launch_bounds__(256)
void cvt_kernel(const float* __restrict__ in, u16* __restrict__ out, int n4) {
  int i = blockIdx.x * 256 + threadIdx.x;
  if (i >= n4) return;
  float4 v = ((const float4*)in)[i];
  union { u16 o[4]; u32x2 d; } t;
  t.o[0] = f2bf(v.x); t.o[1] = f2bf(v.y); t.o[2] = f2bf(v.z); t.o[3] = f2bf(v.w);
  ((u32x2*)out)[i] = t.d;
}

// ---------------- LayerNorm (fp32 in, bf16 out), one row per block ----------------
__global__ __launch_bounds__(256)
void ln_kernel(const float* __restrict__ x, const float* __restrict__ g,
               const float* __restrict__ bta, u16* __restrict__ out) {
  const int row = blockIdx.x, tid = threadIdx.x;
  const int lane = tid & 63, w = tid >> 6;
  const float* xr = x + (size_t)row * HDIM + tid * 8;
  float4 a = *(const float4*)xr;
  float4 c = *(const float4*)(xr + 4);
  float s = a.x + a.y + a.z + a.w + c.x + c.y + c.z + c.w;
  float q = a.x*a.x + a.y*a.y + a.z*a.z + a.w*a.w + c.x*c.x + c.y*c.y + c.z*c.z + c.w*c.w;
#pragma unroll
  for (int m = 32; m >= 1; m >>= 1) { s += __shfl_xor(s, m, 64); q += __shfl_xor(q, m, 64); }
  __shared__ float red[8];
  if (lane == 0) { red[w] = s; red[4 + w] = q; }
  __syncthreads();
  s = red[0] + red[1] + red[2] + red[3];
  q = red[4] + red[5] + red[6] + red[7];
  const float mu = s * (1.0f / HDIM);
  const float rstd = rsqrtf(q * (1.0f / HDIM) - mu * mu + 1e-5f);
  const float* gp = g + tid * 8; const float* bp = bta + tid * 8;
  float4 g0 = *(const float4*)gp, g1 = *(const float4*)(gp + 4);
  float4 b0 = *(const float4*)bp, b1 = *(const float4*)(bp + 4);
  union { u16 o[8]; u32x4 d; } t;
  t.o[0] = f2bf((a.x - mu) * rstd * g0.x + b0.x);
  t.o[1] = f2bf((a.y - mu) * rstd * g0.y + b0.y);
  t.o[2] = f2bf((a.z - mu) * rstd * g0.z + b0.z);
  t.o[3] = f2bf((a.w - mu) * rstd * g0.w + b0.w);
  t.o[4] = f2bf((c.x - mu) * rstd * g1.x + b1.x);
  t.o[5] = f2bf((c.y - mu) * rstd * g1.y + b1.y);
  t.o[6] = f2bf((c.z - mu) * rstd * g1.z + b1.z);
  t.o[7] = f2bf((c.w - mu) * rstd * g1.w + b1.w);
  *(u32x4*)(out + (size_t)row * HDIM + tid * 8) = t.d;
}

// ---------------- GEMM 256x256, BK=64, 2-buf dbuf, 4-phase/K-tile (m201 port) ---
// C[M,N] = A[M,K](bf16) @ B[N,K]^T(bf16) + bias
// EPI 0: bf16 out;  1: GELU(exact) -> bf16 out;  2: + resid(fp32) -> fp32 out
// 512 thr = 8 waves (2M x 4N); per-wave 128x64 out; acc[8][4].
// LDS 128KB = 2 bufs x (A 256x64 + B 256x64). Rows 128B; slot swizzle
//   slot' = slot ^ (row&7)  -> frag reads 2-lanes/bank (free); staged via
//   pre-swizzled global SOURCE col ((tid&7)^((tid>>3)&7))*16 (involution).
// Phases per K-tile t (buf p=t&1), quadrants (0,0),(1,0),(0,1),(1,1),
// A frags held in regs (af0 live P1-P3, af1 P2-P4), B reloaded at P3:
//   P1: ds A(qm0)x8+B(qn0)x4, stage B0(t+1); bar; lgkm0; 16 MFMA; bar
//   P2: ds A(qm1)x8,          stage B1(t+1); bar; lgkm0; 16 MFMA; bar
//   P3: ds B(qn1)x4,          stage A0(t+2); bar; lgkm0; 16 MFMA; bar
//   P4:                       stage A1(t+2);      16 MFMA; vmcnt(4); bar
// WAR: stage dest free (B(t+1): other buf, last read P3(t-1); A(t+2): own buf,
//   A-reads end P2, ordered by BAR2(P2)). RAW: vmcnt(4) leaves exactly
//   A(t+2)'s 4 loads in flight -> tile t+1 fully landed + barrier = visible.
#define GBAR()  __builtin_amdgcn_s_barrier()
#define GLGK0() asm volatile("s_waitcnt lgkmcnt(0)" ::: "memory")
#define GVM(n)  asm volatile("s_waitcnt vmcnt(" #n ")" ::: "memory")

template <int EPI>
__global__ __launch_bounds__(512, 1)
void gemm256(const u16* __restrict__ A, const u16* __restrict__ Bm,
             const float* __restrict__ bias, const float* __restrict__ resid,
             u16* __restrict__ Cb, float* __restrict__ Cf, int M, int N, int K) {
  __shared__ u16 lds[65536];               // 128 KiB = 2 bufs x 64KB
  char* Lb = (char*)lds;
  const int tid = threadIdx.x;
  const int lane = tid & 63, w = tid >> 6;
  const int wm = w >> 2, wn = w & 3;
  const int l15 = lane & 15, hi = lane >> 4;

  // T1: bijective XCD swizzle (all our grids have nwg % 8 == 0)
  const int gx = gridDim.x;
  const int nwg = gx * gridDim.y;
  int wgid = blockIdx.y * gx + blockIdx.x;
  wgid = (wgid & 7) * (nwg >> 3) + (wgid >> 3);
  const int tm = (wgid / gx) * 256, tn = (wgid % gx) * 256;

  const size_t rsK = (size_t)K * 2;        // global row stride (bytes)
  const int srow8 = tid >> 3;              // 0..63: row within 8KB granule
  const int scb   = ((tid & 7) ^ ((tid >> 3) & 7)) * 16;   // pre-swizzled src col
  const char* gA = (const char*)A + (size_t)(tm + srow8) * rsK + scb;
  const char* gB = (const char*)Bm + (size_t)(tn + srow8) * rsK + scb;

  // stage half-tile h (o=0:A,1:B) of K-tile tt into buf tt&1 (2 x 8KB granules)
#define STGH(o, h, tt) do {                                                    \
    char* _d = Lb + ((((tt) & 1) << 16) + (o) * 32768 + (h) * 16384 + tid * 16); \
    const char* _s = (o) ? gB : gA;                                            \
    const size_t _off = (size_t)(tt) * 128 + (size_t)((h) * 128) * rsK;        \
    gload16(_s + _off, _d);                                                    \
    gload16(_s + _off + (size_t)64 * rsK, _d + 8192);                          \
  } while (0)

  // swizzled 16B slot within the 128B row (per-thread constant)
  int koff[2];
#pragma unroll
  for (int ks = 0; ks < 2; ++ks) koff[ks] = ((ks * 4 + hi) ^ (l15 & 7)) * 16;

#define LDA(qm, dst) do {                                                      \
    _Pragma("unroll")                                                          \
    for (int mi4 = 0; mi4 < 4; ++mi4)                                          \
      _Pragma("unroll")                                                        \
      for (int ks = 0; ks < 2; ++ks)                                           \
        dst[mi4][ks] = *(const bf16x8*)(Lb + bb + wm * 16384 +                 \
            ((qm) * 64 + mi4 * 16 + l15) * 128 + koff[ks]);                    \
  } while (0)

#define LDB(qn) do {                                                           \
    _Pragma("unroll")                                                          \
    for (int ni = 0; ni < 2; ++ni)                                             \
      _Pragma("unroll")                                                        \
      for (int ks = 0; ks < 2; ++ks)                                           \
        bf[ni][ks] = *(const bf16x8*)(Lb + bb + 32768 + (wn >> 1) * 16384 +    \
            ((wn & 1) * 64 + (qn) * 32 + ni * 16 + l15) * 128 + koff[ks]);     \
  } while (0)

#define MFMA16(qm, qn, src) do {                                               \
    __builtin_amdgcn_s_setprio(1);                                             \
    _Pragma("unroll")                                                          \
    for (int mi4 = 0; mi4 < 4; ++mi4)                                          \
      _Pragma("unroll")                                                        \
      for (int ni = 0; ni < 2; ++ni)                                           \
        _Pragma("unroll")                                                      \
        for (int ks = 0; ks < 2; ++ks)                                         \
          acc[(qm) * 4 + mi4][(qn) * 2 + ni] =                                 \
            __builtin_amdgcn_mfma_f32_16x16x32_bf16(src[mi4][ks], bf[ni][ks],  \
                acc[(qm) * 4 + mi4][(qn) * 2 + ni], 0, 0, 0);                  \
    __builtin_amdgcn_s_setprio(0);                                             \
  } while (0)

  f32x4 acc[8][4] = {};
  bf16x8 af0[4][2], af1[4][2], bf[2][2];

  const int NT = K >> 6;                   // K-tiles of 64 (NT >= 2 always here)

  // prologue: tile 0 fully + A halves of tile 1; gate leaves A(1) in flight
  STGH(0, 0, 0); STGH(0, 1, 0); STGH(1, 0, 0); STGH(1, 1, 0);
  STGH(0, 0, 1); STGH(0, 1, 1);
  GVM(4); GBAR();

  for (int t = 0; t < NT; ++t) {
    const int bb = (t & 1) << 16;
    const bool sB = (t + 1 < NT), sA = (t + 2 < NT);
    // P1
    LDA(0, af0); LDB(0);
    if (sB) STGH(1, 0, t + 1);
    GBAR(); GLGK0(); MFMA16(0, 0, af0); GBAR();
    // P2
    LDA(1, af1);
    if (sB) STGH(1, 1, t + 1);
    GBAR(); GLGK0(); MFMA16(1, 0, af1); GBAR();
    // P3
    LDB(1);
    if (sA) STGH(0, 0, t + 2);
    GBAR(); GLGK0(); MFMA16(0, 1, af0); GBAR();
    // P4 (no ds reads; stage ordered after BAR2(P2) vs A-reads)
    if (sA) STGH(0, 1, t + 2);
    MFMA16(1, 1, af1);
    if (sA) GVM(4); else GVM(0);
    GBAR();
  }

  // epilogue
#pragma unroll
  for (int mi = 0; mi < 8; ++mi) {
#pragma unroll
    for (int ni = 0; ni < 4; ++ni) {
      const int col = tn + wn * 64 + ni * 16 + l15;
      const float bv = bias[col];
#pragma unroll
      for (int r = 0; r < 4; ++r) {
        const int row = tm + wm * 128 + mi * 16 + hi * 4 + r;
        float v = acc[mi][ni][r] + bv;
        if constexpr (EPI == 1) v = 0.5f * v * (1.0f + erff(v * 0.70710678118654752f));
        const size_t idx = (size_t)row * N + col;
        if constexpr (EPI == 2) Cf[idx] = v + resid[idx];
        else                    Cb[idx] = f2bf(v);
      }
    }
  }
#undef STGH
#undef LDA
#undef LDB
#undef MFMA16
}

// ---------------- V transpose: qkv V part -> Vt_g[bh][d][s] ----------------
__global__ __launch_bounds__(256)
void vtrans_kernel(const u16* __restrict__ qkv, u16* __restrict__ vt) {
  __shared__ u16 tile[32 * 136];
  const int s0 = blockIdx.x * 32;
  const int bh = blockIdx.y;
  const int b = bh >> 4, h = bh & 15;
  const int t = threadIdx.x;
  const int srow = t >> 3, scol = (t & 7) * 16;
  const u16* src = qkv + (size_t)((s0 + srow) * 4 + b) * H3 + 4096 + h * 128 + scol;
  *(bf16x8*)(tile + srow * 136 + scol)     = *(const bf16x8*)src;
  *(bf16x8*)(tile + srow * 136 + scol + 8) = *(const bf16x8*)(src + 8);
  __syncthreads();
  const int d = t >> 1, sc = (t & 1) * 16;
  union { u16 o[16]; u32x4 q[2]; } tmp;
#pragma unroll
  for (int i = 0; i < 16; ++i) tmp.o[i] = tile[(sc + i) * 136 + d];
  u16* dst = vt + ((size_t)bh * 128 + d) * 2048 + s0 + sc;
  *(u32x4*)dst       = tmp.q[0];
  *(u32x4*)(dst + 8) = tmp.q[1];
}

// ---------------- Flash attention (causal, 16 heads, HD=128) ----------------
__global__ __launch_bounds__(256, 2)
void attn_kernel(const u16* __restrict__ qkv, const u16* __restrict__ vt,
                 u16* __restrict__ outb) {
  const int qt = 31 - blockIdx.x;          // long blocks dispatch first
  const int bh = blockIdx.y;
  const int b = bh >> 4, h = bh & 15;
  const int tid = threadIdx.x, lane = tid & 63, w = tid >> 6;
  const int hi = lane >> 4, l15 = lane & 15;
  const int qs = qt * 64;

  __shared__ u16 Klds[64 * 128];           // [kv][d], rows 256B, swizzled
  __shared__ u16 Vlds[128 * 64];           // [d][kv], rows 128B, swizzled
  __shared__ u16 Plds[4 * 16 * 64];        // per-wave [16 q][64 kv], swizzled

  bf16x8 qf[4];
  {
    const int qrow = qs + w * 16 + l15;
    const u16* qp = qkv + (size_t)(qrow * 4 + b) * H3 + h * 128 + hi * 8;
#pragma unroll
    for (int kc = 0; kc < 4; ++kc) qf[kc] = *(const bf16x8*)(qp + kc * 32);
  }

  f32x4 o[8] = {};
  float mrun[4], lrun[4];
#pragma unroll
  for (int r = 0; r < 4; ++r) { mrun[r] = -1e30f; lrun[r] = 0.0f; }

  const float sc = 0.08838834764831845f;   // 1/sqrt(128)
  char* plb = (char*)(Plds + w * 1024);

  const int krow = tid >> 2;               // 0..63 kv row
  const int kcb  = (tid & 3) * 64;         // byte col in K row
  const int vd   = tid >> 1;               // 0..127 d row
  const int vhb  = (tid & 1) * 64;         // byte col in Vt row

  const int ntiles = qt + 1;
  for (int kt = 0; kt < ntiles; ++kt) {
    const int kv0 = kt * 64;
    const u16* ksrc = qkv + (size_t)((kv0 + krow) * 4 + b) * H3 + 2048 + h * 128 + kcb / 2;
    const u16* vsrc = vt + ((size_t)bh * 128 + vd) * 2048 + kv0 + (tid & 1) * 32;
    bf16x8 kr[4], vr[4];
#pragma unroll
    for (int c = 0; c < 4; ++c) { kr[c] = *(const bf16x8*)(ksrc + c * 8); vr[c] = *(const bf16x8*)(vsrc + c * 8); }

    __syncthreads();
#pragma unroll
    for (int c = 0; c < 4; ++c) {
      *(bf16x8*)((char*)Klds + ((krow * 256 + kcb + c * 16) ^ ((krow & 7) << 4))) = kr[c];
      *(bf16x8*)((char*)Vlds + ((vd * 128 + vhb + c * 16) ^ ((vd & 7) << 4)))     = vr[c];
    }
    __syncthreads();

    f32x4 s[4] = {};
#pragma unroll
    for (int kc = 0; kc < 4; ++kc) {
      const int dbyte = kc * 64 + hi * 16;
#pragma unroll
      for (int g = 0; g < 4; ++g) {
        const int row = g * 16 + l15;
        bf16x8 kf = *(const bf16x8*)((char*)Klds + ((row * 256 + dbyte) ^ ((l15 & 7) << 4)));
        s[g] = __builtin_amdgcn_mfma_f32_16x16x32_bf16(qf[kc], kf, s[g], 0, 0, 0);
      }
    }
#pragma unroll
    for (int g = 0; g < 4; ++g)
#pragma unroll
      for (int r = 0; r < 4; ++r) s[g][r] *= sc;

    if (kt == qt) {
#pragma unroll
      for (int g = 0; g < 4; ++g)
#pragma unroll
        for (int r = 0; r < 4; ++r) {
          const int qrel = w * 16 + hi * 4 + r;
          if (g * 16 + l15 > qrel) s[g][r] = -1e30f;
        }
    }

    float pm[4];
#pragma unroll
    for (int r = 0; r < 4; ++r)
      pm[r] = fmaxf(fmaxf(s[0][r], s[1][r]), fmaxf(s[2][r], s[3][r]));
#pragma unroll
    for (int m = 8; m >= 1; m >>= 1)
#pragma unroll
      for (int r = 0; r < 4; ++r) pm[r] = fmaxf(pm[r], __shfl_xor(pm[r], m, 64));

    float corr[4], rs[4];
    float p[4][4];
#pragma unroll
    for (int r = 0; r < 4; ++r) {
      const float mnew = fmaxf(mrun[r], pm[r]);
      corr[r] = __expf(mrun[r] - mnew);
      mrun[r] = mnew;
      rs[r] = 0.0f;
    }
#pragma unroll
    for (int g = 0; g < 4; ++g)
#pragma unroll
      for (int r = 0; r < 4; ++r) { p[g][r] = __expf(s[g][r] - mrun[r]); rs[r] += p[g][r]; }
#pragma unroll
    for (int m = 8; m >= 1; m >>= 1)
#pragma unroll
      for (int r = 0; r < 4; ++r) rs[r] += __shfl_xor(rs[r], m, 64);
#pragma unroll
    for (int r = 0; r < 4; ++r) lrun[r] = lrun[r] * corr[r] + rs[r];
#pragma unroll
    for (int nf = 0; nf < 8; ++nf)
#pragma unroll
      for (int r = 0; r < 4; ++r) o[nf][r] *= corr[r];

#pragma unroll
    for (int r = 0; r < 4; ++r) {
      const int prow = hi * 4 + r;
      const int sw = (prow & 7) << 4;
#pragma unroll
      for (int g = 0; g < 4; ++g)
        *(u16*)(plb + ((prow * 128 + (g * 16 + l15) * 2) ^ sw)) = f2bf(p[g][r]);
    }
    asm volatile("s_waitcnt lgkmcnt(0)" ::: "memory");
    bf16x8 pf[2];
#pragma unroll
    for (int hk = 0; hk < 2; ++hk)
      pf[hk] = *(const bf16x8*)(plb + ((l15 * 128 + hk * 64 + hi * 16) ^ ((l15 & 7) << 4)));

#pragma unroll
    for (int hk = 0; hk < 2; ++hk)
#pragma unroll
      for (int nf = 0; nf < 8; ++nf) {
        bf16x8 vf = *(const bf16x8*)((char*)Vlds +
                      (((nf * 16 + l15) * 128 + hk * 64 + hi * 16) ^ ((l15 & 7) << 4)));
        o[nf] = __builtin_amdgcn_mfma_f32_16x16x32_bf16(pf[hk], vf, o[nf], 0, 0, 0);
      }
  }

  float inv[4];
#pragma unroll
  for (int r = 0; r < 4; ++r) inv[r] = 1.0f / lrun[r];
#pragma unroll
  for (int nf = 0; nf < 8; ++nf) {
#pragma unroll
    for (int r = 0; r < 4; ++r) {
      const int rl = hi * 4 + r;
      const int t = (qs + w * 16 + rl) * 4 + b;
      outb[(size_t)t * HDIM + h * 128 + nf * 16 + l15] = f2bf(o[nf][r] * inv[r]);
    }
  }
}

// ---------------- launcher ----------------
extern "C" void kernel_launch(void* const* d_in, const int* in_sizes, int n_in,
                              void* d_out, int out_size, void* d_ws, size_t ws_size,
                              hipStream_t stream) {
  const float* x     = (const float*)d_in[0];
  const float* ln1g  = (const float*)d_in[1];
  const float* ln1b  = (const float*)d_in[2];
  const float* qkvw  = (const float*)d_in[3];
  const float* qkvb  = (const float*)d_in[4];
  const float* projw = (const float*)d_in[5];
  const float* projb = (const float*)d_in[6];
  const float* ln2g  = (const float*)d_in[7];
  const float* ln2b  = (const float*)d_in[8];
  const float* fc1w  = (const float*)d_in[9];
  const float* fc1b  = (const float*)d_in[10];
  const float* fc2w  = (const float*)d_in[11];
  const float* fc2b  = (const float*)d_in[12];
  float* out = (float*)d_out;

  // ws layout (192 MiB):
  //   [0,32M)    wbuf (weights bf16)             -- dead during attention
  //   [32M,64M)  pbuf (LN outputs bf16)          -- dead during attention
  //   [0,64M)    vtg  (V transposed, attn-only)  -- overlaps wbuf+pbuf
  //   [64M,192M) qbuf (qkv / fc1 out bf16)
  //   [160M,192M) aout (attn out, dead region of qbuf during attn)
  u16* wbuf = (u16*)d_ws;
  u16* pbuf = (u16*)((char*)d_ws + (size_t)32 * 1024 * 1024);
  u16* qbuf = (u16*)((char*)d_ws + (size_t)64 * 1024 * 1024);
  u16* vtg  = (u16*)d_ws;
  u16* aout = (u16*)((char*)d_ws + (size_t)160 * 1024 * 1024);

  dim3 blk(256);
  dim3 gblk(512);

  // LN1 -> pbuf (bf16)
  ln_kernel<<<8192, blk, 0, stream>>>(x, ln1g, ln1b, pbuf);
  // qkv_w -> bf16
  cvt_kernel<<<12288, blk, 0, stream>>>(qkvw, wbuf, 3145728);
  // qkv = h @ qkv_w^T + b  -> qbuf [8192 x 6144] bf16   (grid 24x32 = 768 blocks)
  gemm256<0><<<dim3(24, 32), gblk, 0, stream>>>(pbuf, wbuf, qkvb, nullptr, qbuf, nullptr, 8192, 6144, 2048);
  // V -> Vt_g [bh][d][s]
  vtrans_kernel<<<dim3(64, 64), blk, 0, stream>>>(qbuf, vtg);
  // attention -> aout [8192 x 2048] bf16
  attn_kernel<<<dim3(32, 64), blk, 0, stream>>>(qbuf, vtg, aout);
  // proj_w -> bf16 (vtg dead now)
  cvt_kernel<<<4096, blk, 0, stream>>>(projw, wbuf, 1048576);
  // x2 = x + attn @ proj_w^T + b  -> d_out (fp32)   (grid 8x32 = 256)
  gemm256<2><<<dim3(8, 32), gblk, 0, stream>>>(aout, wbuf, projb, x, nullptr, out, 8192, 2048, 2048);
  // LN2 -> pbuf (bf16)
  ln_kernel<<<8192, blk, 0, stream>>>(out, ln2g, ln2b, pbuf);
  // fc1_w -> bf16
  cvt_kernel<<<16384, blk, 0, stream>>>(fc1w, wbuf, 4194304);
  // h = gelu(ln2 @ fc1_w^T + b) -> qbuf [8192 x 8192] bf16   (grid 32x32 = 1024)
  gemm256<1><<<dim3(32, 32), gblk, 0, stream>>>(pbuf, wbuf, fc1b, nullptr, qbuf, nullptr, 8192, 8192, 2048);
  // fc2_w -> bf16
  cvt_kernel<<<16384, blk, 0, stream>>>(fc2w, wbuf, 4194304);
  // out = x2 + h @ fc2_w^T + b  (in-place residual on d_out)   (grid 8x32, K=8192)
  gemm256<2><<<dim3(8, 32), gblk, 0, stream>>>(qbuf, wbuf, fc2b, out, nullptr, out, 8192, 2048, 8192);
}